// Round 1
// baseline (441.190 us; speedup 1.0000x reference)
//
#include <hip/hip_runtime.h>
#include <math.h>

#define B_ 2
#define L_ 1024
#define DM_ 1024
#define STATE_ 16
#define CONV_ 4
#define DTR_ 8
#define INNER_ 2048
#define M_ (B_*L_)        /* 2048 rows (b,l) */
#define MD_ (B_*INNER_)   /* 4096 rows (b,c) */
#define NFFT_ 513
#define NFP_ 1152         /* 2*513=1026 padded to multiple of 128 */
#define NCH_ 32
#define CHL_ 32
#define SK_ 32            /* x_proj split-K factor */
#define KSL_ (2048/SK_)   /* 64 */

typedef unsigned short u16;
typedef __attribute__((ext_vector_type(8))) short short8;
typedef __attribute__((ext_vector_type(8))) __bf16 bf16x8;
typedef __attribute__((ext_vector_type(4))) float f32x4;

__device__ __forceinline__ float frcp_(float x) { return __builtin_amdgcn_rcpf(x); }
__device__ __forceinline__ float fexp_(float x) { return __expf(x); }
__device__ __forceinline__ float fsigm_(float x) { return frcp_(1.f + __expf(-x)); }
__device__ __forceinline__ float fsilu_(float x) { return x * frcp_(1.f + __expf(-x)); }
__device__ __forceinline__ float fsoftplus_(float v) {
  return (v > 20.f) ? v : __logf(1.f + __expf(v));
}
__device__ __forceinline__ u16 f2bf(float f) {
  union { float f; unsigned u; } v; v.f = f;
  unsigned r = v.u + 0x7fffu + ((v.u >> 16) & 1u);
  return (u16)(r >> 16);
}
__device__ __forceinline__ float bf2f(u16 h) {
  union { unsigned u; float f; } v; v.u = ((unsigned)h) << 16;
  return v.f;
}
__device__ __forceinline__ void gload16(const void* g, void* l) {
  __builtin_amdgcn_global_load_lds(
      (const __attribute__((address_space(1))) unsigned*)g,
      (__attribute__((address_space(3))) unsigned*)l, 16, 0, 0);
}
__device__ __forceinline__ f32x4 mfma_bf16(short8 a, short8 b, f32x4 c) {
  return __builtin_amdgcn_mfma_f32_16x16x32_bf16(
      __builtin_bit_cast(bf16x8, a), __builtin_bit_cast(bf16x8, b), c, 0, 0, 0);
}

// ---------------- fp32 -> bf16 conversion (4 sources, contiguous dst) -------
#define CVT_N0 2097152
#define CVT_N1 6291456
#define CVT_N2 14680064
#define CVT_NT 16777216
__global__ __launch_bounds__(256) void cvt4_k(
    const float* __restrict__ s0, const float* __restrict__ s1,
    const float* __restrict__ s2, const float* __restrict__ s3,
    u16* __restrict__ out)
{
  int i = (blockIdx.x*256 + threadIdx.x) * 4;
  const float* src; int off;
  if (i < CVT_N0)      { src = s0; off = 0; }
  else if (i < CVT_N1) { src = s1; off = CVT_N0; }
  else if (i < CVT_N2) { src = s2; off = CVT_N1; }
  else                 { src = s3; off = CVT_N2; }
  float4 v = *(const float4*)(src + (i - off));
  ushort4 o;
  o.x = f2bf(v.x); o.y = f2bf(v.y); o.z = f2bf(v.z); o.w = f2bf(v.w);
  *(ushort4*)(out + i) = o;
}

// ---------------- bf16 MFMA GEMM (templated tile, triple-buffered) ----------
// C[m,n] = sum_k A[m,k]*Bt[n,k].  A: M x K bf16, Bt: N x K bf16, K%64==0.
// Wave sub-tile 64x32 (acc 4x2); waves = (TM/64)*(TN/32).
// Pipeline: 3 LDS buffers, prefetch depth 2, counted vmcnt (never 0 in the
// steady-state loop) + raw s_barrier so next-tile global_load_lds stay in
// flight across the barrier (T3+T4 minimal form; avoids the compiler's
// vmcnt(0) drain that __syncthreads() forces).
// EPI: 0 plain f32; 1 fusion gate (bf16); 2 residual add (f32);
//      3 spectral filter (bf16); 5 in_proj (f32 + transposed bf16 xt);
//      6 inv-DFT (bf16 transposed into ycat).
template<int TM, int TN, int EPI>
__global__ __launch_bounds__((TM/64)*(TN/32)*64) void mgemm_k(
    const u16* __restrict__ Ab, const u16* __restrict__ Bb,
    void* __restrict__ Cout, int K, int ldc,
    const float* __restrict__ aux0, u16* __restrict__ aux1,
    const float* __restrict__ aux2, const float* __restrict__ aux3)
{
  constexpr int WN   = TN/32;
  constexpr int NW   = (TM/64)*WN;
  constexpr int NTHR = NW*64;
  constexpr int LPS  = (TM + TN)*8/NTHR;   // gload16 per thread per stage
  __shared__ __align__(16) u16 As[3][TM*64];
  __shared__ __align__(16) u16 Bs[3][TN*64];
  const int t = threadIdx.x;
  const int lane = t & 63;
  const int w = t >> 6;
  const int wm = w / WN, wn = w % WN;
  const int M0 = blockIdx.y * TM, N0 = blockIdx.x * TN;

  f32x4 acc[4][2] = {};

  auto stage = [&](int bufi, int k0) {
    #pragma unroll
    for (int q = 0; q < TM*8/NTHR; q++) {
      int u = q*NTHR + t;
      int row = u >> 3, gpr = u & 7;
      int grp = gpr ^ (row & 7);        // XOR swizzle
      gload16(Ab + (size_t)(M0+row)*K + k0 + grp*8, &As[bufi][u*8]);
    }
    #pragma unroll
    for (int q = 0; q < TN*8/NTHR; q++) {
      int u = q*NTHR + t;
      int row = u >> 3, gpr = u & 7;
      int grp = gpr ^ (row & 7);
      gload16(Bb + (size_t)(N0+row)*K + k0 + grp*8, &Bs[bufi][u*8]);
    }
  };

  const int nk = K >> 6;                // nk >= 16 for all call sites
  stage(0, 0);
  stage(1, 1 << 6);
  int buf = 0, sb = 2;
  for (int ks = 0; ks < nk; ks++) {
    // Drain exactly the tile we are about to compute; keep the next tile's
    // LPS loads in flight (vmcnt retires oldest-first, so <=LPS outstanding
    // means stage(ks) has fully landed in LDS).
    if (ks + 1 < nk) {
      asm volatile("s_waitcnt vmcnt(%0)" :: "i"(LPS) : "memory");
    } else {
      asm volatile("s_waitcnt vmcnt(0)" ::: "memory");
    }
    __builtin_amdgcn_sched_barrier(0);
    __builtin_amdgcn_s_barrier();       // raw barrier: no implicit vmcnt(0)
    __builtin_amdgcn_sched_barrier(0);
    if (ks + 2 < nk) stage(sb, (ks + 2) << 6);
    const u16* Asb = As[buf];
    const u16* Bsb = Bs[buf];
    #pragma unroll
    for (int kk = 0; kk < 2; kk++) {
      const int quad = lane >> 4;
      const int grp = kk*4 + quad;
      short8 af[4], bfr[2];
      #pragma unroll
      for (int i = 0; i < 4; i++) {
        int row = wm*64 + i*16 + (lane & 15);
        af[i] = *(const short8*)&Asb[(row*8 + (grp ^ (row & 7)))*8];
      }
      #pragma unroll
      for (int j = 0; j < 2; j++) {
        int row = wn*32 + j*16 + (lane & 15);
        bfr[j] = *(const short8*)&Bsb[(row*8 + (grp ^ (row & 7)))*8];
      }
      #pragma unroll
      for (int i = 0; i < 4; i++)
        #pragma unroll
        for (int j = 0; j < 2; j++)
          acc[i][j] = mfma_bf16(af[i], bfr[j], acc[i][j]);
    }
    buf = (buf == 2) ? 0 : buf + 1;
    sb  = (sb  == 2) ? 0 : sb + 1;
  }

  // C/D layout: col = lane&15, row = (lane>>4)*4 + r
  #pragma unroll
  for (int i = 0; i < 4; i++) {
    int mbase = M0 + wm*64 + i*16 + (lane >> 4)*4;
    #pragma unroll
    for (int j = 0; j < 2; j++) {
      int n = N0 + wn*32 + j*16 + (lane & 15);
      #pragma unroll
      for (int r = 0; r < 4; r++) {
        int m = mbase + r;
        float v = acc[i][j][r];
        if (EPI == 0) {
          ((float*)Cout)[(size_t)m*ldc + n] = v;
        } else if (EPI == 1) {          // fusion gate
          float g  = fsigm_(v + aux0[n]);
          float ys = bf2f(aux1[(size_t)m*4096 + n]);
          float yp = bf2f(aux1[(size_t)m*4096 + 2048 + n]);
          float z  = aux2[(size_t)m*4096 + 2048 + n];
          ((u16*)Cout)[(size_t)m*ldc + n] = f2bf((g*ys + (1.f-g)*yp)*fsilu_(z));
        } else if (EPI == 2) {          // residual add
          ((float*)Cout)[(size_t)m*ldc + n] = v + aux2[(size_t)m*ldc + n];
        } else if (EPI == 3) {          // spectral filter, complex pair via shfl
          float pv = __shfl_xor(v, 1, 64);
          int f = n >> 1;
          float outv = 0.f;
          if (f < NFFT_) {
            int c = m & (INNER_-1);
            float d  = fexp_(-aux2[c] * (float)f * (1.f/512.f));
            float wr = aux0[c*NFFT_+f]*d, wi = aux3[c*NFFT_+f]*d;
            float a = (n & 1) ? pv : v;
            float b = (n & 1) ? v : pv;
            outv = (n & 1) ? (a*wi + b*wr) : (a*wr - b*wi);
          }
          ((u16*)Cout)[(size_t)m*ldc + n] = f2bf(outv);
        } else if (EPI == 5) {          // in_proj: xz f32 + transposed bf16 xt
          ((float*)Cout)[(size_t)m*ldc + n] = v;
          if (n < 2048) {
            int b2 = m >> 10, l2 = m & 1023;
            aux1[((size_t)(b2*2048 + n) << 10) + l2] = f2bf(v);
          }
        } else {                        // 6: inv-DFT transposed into ycat
          int b2 = m >> 11, c2 = m & (INNER_-1);
          ((u16*)Cout)[((size_t)((b2 << 10) + n) << 12) + 2048 + c2] = f2bf(v);
        }
      }
    }
  }
}

// ---------------- x_proj split-K: part[sk][m][40] = xconv[m, sk*64:+64] @ W^T ----
__global__ __launch_bounds__(256) void xproj_k(
    const float* __restrict__ xconv, const float* __restrict__ W,
    float* __restrict__ part)
{
  __shared__ float Bs[40][KSL_+4];
  const int sk = blockIdx.x, mt = blockIdx.y;
  const int k0 = sk*KSL_;
  for (int i = threadIdx.x; i < 40*KSL_; i += 256) {
    int n = i >> 6, k = i & (KSL_-1);
    Bs[n][k] = W[(size_t)n*2048 + k0 + k];
  }
  __syncthreads();
  const int m = mt*256 + threadIdx.x;
  const float* arow = xconv + (size_t)m*2048 + k0;
  float acc[40];
  #pragma unroll
  for (int j=0;j<40;j++) acc[j]=0.f;
  for (int k = 0; k < KSL_; k += 4) {
    float4 a = *(const float4*)(arow + k);
    #pragma unroll
    for (int j = 0; j < 40; j++) {
      float4 b = *(const float4*)&Bs[j][k];
      acc[j] += a.x*b.x + a.y*b.y + a.z*b.z + a.w*b.w;
    }
  }
  float* o = part + ((size_t)sk*M_ + m)*40;
  #pragma unroll
  for (int j = 0; j < 10; j++)
    *(float4*)(o + j*4) = make_float4(acc[j*4], acc[j*4+1], acc[j*4+2], acc[j*4+3]);
}

__global__ __launch_bounds__(256) void xpred_k(const float* __restrict__ part,
                                               float* __restrict__ xdbc)
{
  int i = blockIdx.x*256 + threadIdx.x;   // 81920 total
  float s = 0.f;
  #pragma unroll
  for (int sk = 0; sk < SK_; sk++) s += part[(size_t)sk*81920 + i];
  xdbc[i] = s;
}

// ---------------- depthwise causal conv(4) + silu, 8 l per thread ----------
__global__ __launch_bounds__(256) void conv_silu_k(
    const float* __restrict__ xz, const float* __restrict__ cw,
    const float* __restrict__ cb, float* __restrict__ xc)
{
  int idx = blockIdx.x*256 + threadIdx.x;   // 524288 total
  int c = idx & (INNER_-1);
  int g = idx >> 11;                        // 0..255
  int b = g >> 7;
  int lb = (g & 127) * 8;
  float w0=cw[c*4+0], w1=cw[c*4+1], w2=cw[c*4+2], w3=cw[c*4+3];
  float bias = cb[c];
  float v[11];
  #pragma unroll
  for (int j = 0; j < 11; j++) {
    int l = lb - 3 + j;
    v[j] = (l >= 0) ? xz[((size_t)((b << 10) + l))*4096 + c] : 0.f;
  }
  #pragma unroll
  for (int j = 0; j < 8; j++) {
    float s = bias + w0*v[j] + w1*v[j+1] + w2*v[j+2] + w3*v[j+3];
    xc[((size_t)((b << 10) + lb + j))*INNER_ + c] = fsilu_(s);
  }
}

// ---------------- SSM chunked scan (prefetched) ----------------
// Pq layout per (b,ch,e): [0..15] = P (chunk transfer), [16..31] = q, then
// scan2 overwrites q-slot with h_in for that chunk.
__global__ __launch_bounds__(256) void scan1_k(
    const float* __restrict__ xdbc, const float* __restrict__ xconv,
    const float* __restrict__ A_log, const float* __restrict__ dtw,
    const float* __restrict__ dtb, float* __restrict__ Pq)
{
  int idx = blockIdx.x*256 + threadIdx.x;   // (b*NCH+ch)*INNER + e
  int e  = idx & (INNER_-1);
  int bc = idx >> 11;
  int ch = bc & (NCH_-1);
  int b  = bc >> 5;
  float A[STATE_];
  #pragma unroll
  for (int s=0;s<STATE_;s++) A[s] = -fexp_(A_log[e*STATE_+s]);
  float w[DTR_];
  #pragma unroll
  for (int r=0;r<DTR_;r++) w[r] = dtw[e*DTR_+r];
  float bias = dtb[e];
  float h[STATE_] = {};
  float sdt = 0.f;
  int mbase = b*L_ + ch*CHL_;
  // current-step inputs
  float dtx[DTR_], Bv[STATE_], xcv;
  {
    const float* row = xdbc + (size_t)mbase*40;
    #pragma unroll
    for (int r=0;r<DTR_;r++) dtx[r] = row[r];
    #pragma unroll
    for (int s=0;s<STATE_;s++) Bv[s] = row[8+s];
    xcv = xconv[(size_t)mbase*INNER_ + e];
  }
  for (int l=0;l<CHL_;l++) {
    float ndtx[DTR_], nBv[STATE_], nxcv = 0.f;
    if (l+1 < CHL_) {                 // prefetch next step
      const float* nrow = xdbc + (size_t)(mbase+l+1)*40;
      #pragma unroll
      for (int r=0;r<DTR_;r++) ndtx[r] = nrow[r];
      #pragma unroll
      for (int s=0;s<STATE_;s++) nBv[s] = nrow[8+s];
      nxcv = xconv[(size_t)(mbase+l+1)*INNER_ + e];
    } else {
      #pragma unroll
      for (int r=0;r<DTR_;r++) ndtx[r] = 0.f;
      #pragma unroll
      for (int s=0;s<STATE_;s++) nBv[s] = 0.f;
    }
    float v = bias;
    #pragma unroll
    for (int r=0;r<DTR_;r++) v += dtx[r]*w[r];
    float dt = fsoftplus_(v);
    sdt += dt;
    float dx = dt * xcv;
    #pragma unroll
    for (int s=0;s<STATE_;s++) {
      float dA = fexp_(dt*A[s]);
      h[s] = dA*h[s] + dx*Bv[s];
    }
    #pragma unroll
    for (int r=0;r<DTR_;r++) dtx[r] = ndtx[r];
    #pragma unroll
    for (int s=0;s<STATE_;s++) Bv[s] = nBv[s];
    xcv = nxcv;
  }
  float* o = Pq + (size_t)idx*32;
  #pragma unroll
  for (int s=0;s<STATE_;s++) { o[s] = fexp_(A[s]*sdt); o[16+s] = h[s]; }
}

// combine chunks, parallel over (b,e,s); h_in written into the q slot
__global__ __launch_bounds__(256) void scan2_k(float* __restrict__ Pq)
{
  int idx = blockIdx.x*256 + threadIdx.x;   // b*(INNER*16) + e*16 + s ; 65536
  int s = idx & 15;
  int e = (idx >> 4) & (INNER_-1);
  int b = idx >> 15;
  float h = 0.f;
  for (int ch = 0; ch < NCH_; ch++) {
    size_t base = ((size_t)(b*NCH_+ch)*INNER_ + e)*32;
    float p = Pq[base + s];
    float q = Pq[base + 16 + s];
    Pq[base + 16 + s] = h;
    h = p*h + q;
  }
}

__global__ __launch_bounds__(256) void scan3_k(
    const float* __restrict__ xdbc, const float* __restrict__ xconv,
    const float* __restrict__ A_log, const float* __restrict__ dtw,
    const float* __restrict__ dtb, const float* __restrict__ Dp,
    const float* __restrict__ Pq, u16* __restrict__ ycat)
{
  int idx = blockIdx.x*256 + threadIdx.x;
  int e  = idx & (INNER_-1);
  int bc = idx >> 11;
  int ch = bc & (NCH_-1);
  int b  = bc >> 5;
  float A[STATE_];
  #pragma unroll
  for (int s=0;s<STATE_;s++) A[s] = -fexp_(A_log[e*STATE_+s]);
  float w[DTR_];
  #pragma unroll
  for (int r=0;r<DTR_;r++) w[r] = dtw[e*DTR_+r];
  float bias = dtb[e];
  float Dv = Dp[e];
  float h[STATE_];
  const float* hi = Pq + (size_t)idx*32 + 16;
  #pragma unroll
  for (int s=0;s<STATE_;s++) h[s] = hi[s];
  int mbase = b*L_ + ch*CHL_;
  float dtx[DTR_], Bv[STATE_], Cv[STATE_], xcv;
  {
    const float* row = xdbc + (size_t)mbase*40;
    #pragma unroll
    for (int r=0;r<DTR_;r++) dtx[r] = row[r];
    #pragma unroll
    for (int s=0;s<STATE_;s++) { Bv[s] = row[8+s]; Cv[s] = row[24+s]; }
    xcv = xconv[(size_t)mbase*INNER_ + e];
  }
  for (int l=0;l<CHL_;l++) {
    float ndtx[DTR_], nBv[STATE_], nCv[STATE_], nxcv = 0.f;
    if (l+1 < CHL_) {
      const float* nrow = xdbc + (size_t)(mbase+l+1)*40;
      #pragma unroll
      for (int r=0;r<DTR_;r++) ndtx[r] = nrow[r];
      #pragma unroll
      for (int s=0;s<STATE_;s++) { nBv[s] = nrow[8+s]; nCv[s] = nrow[24+s]; }
      nxcv = xconv[(size_t)(mbase+l+1)*INNER_ + e];
    } else {
      #pragma unroll
      for (int r=0;r<DTR_;r++) ndtx[r] = 0.f;
      #pragma unroll
      for (int s=0;s<STATE_;s++) { nBv[s] = 0.f; nCv[s] = 0.f; }
    }
    float v = bias;
    #pragma unroll
    for (int r=0;r<DTR_;r++) v += dtx[r]*w[r];
    float dt = fsoftplus_(v);
    float dx = dt * xcv;
    float y = 0.f;
    #pragma unroll
    for (int s=0;s<STATE_;s++) {
      float dA = fexp_(dt*A[s]);
      h[s] = dA*h[s] + dx*Bv[s];
      y += h[s]*Cv[s];
    }
    ycat[(size_t)(mbase+l)*4096 + e] = f2bf(y + xcv*Dv);
    #pragma unroll
    for (int r=0;r<DTR_;r++) dtx[r] = ndtx[r];
    #pragma unroll
    for (int s=0;s<STATE_;s++) { Bv[s] = nBv[s]; Cv[s] = nCv[s]; }
    xcv = nxcv;
  }
}

// ---------------- DFT matrix generation (bf16, K-contiguous) ----------------
__global__ __launch_bounds__(256) void genWdftb_k(u16* __restrict__ W) {
  int idx = blockIdx.x*256 + threadIdx.x;  // col*1024 + l ; col < NFP_
  int l = idx & (L_-1);
  int col = idx >> 10;
  float v = 0.f;
  int f = col >> 1;
  if (f < NFFT_) {
    int ph = (l*f) & (L_-1);
    float th = (float)ph * (6.283185307179586f / (float)L_);
    v = (col & 1) ? -__sinf(th) : __cosf(th);
  }
  W[idx] = f2bf(v);
}

__global__ __launch_bounds__(256) void genWinvb_k(u16* __restrict__ W) {
  int idx = blockIdx.x*256 + threadIdx.x;  // l*NFP_ + r
  int r = idx % NFP_;
  int l = idx / NFP_;
  int f = r >> 1;
  float v = 0.f;
  if (f < NFFT_) {
    bool edge = (f == 0) || (f == 512);
    float sc = (edge ? 1.f : 2.f) / (float)L_;
    int ph = (f*l) & (L_-1);
    float th = (float)ph * (6.283185307179586f / (float)L_);
    if (r & 1) v = edge ? 0.f : -sc*__sinf(th);
    else       v = sc*__cosf(th);
  }
  W[idx] = f2bf(v);
}

// ---------------- layernorm ----------------
__global__ __launch_bounds__(256) void ln_k(const float* __restrict__ inp,
    const float* __restrict__ gma, const float* __restrict__ bta,
    float* __restrict__ out)
{
  int m = blockIdx.x;
  const float* row = inp + (size_t)m*DM_;
  float s=0.f, s2=0.f;
  float v[4];
  #pragma unroll
  for (int j=0;j<4;j++) {
    v[j] = row[threadIdx.x + j*256];
    s += v[j]; s2 += v[j]*v[j];
  }
  #pragma unroll
  for (int off=32; off>=1; off>>=1) {
    s  += __shfl_down(s, off);
    s2 += __shfl_down(s2, off);
  }
  __shared__ float rs[4], rs2[4], stats[2];
  int wid = threadIdx.x >> 6;
  if ((threadIdx.x & 63) == 0) { rs[wid]=s; rs2[wid]=s2; }
  __syncthreads();
  if (threadIdx.x == 0) {
    float ts  = rs[0]+rs[1]+rs[2]+rs[3];
    float ts2 = rs2[0]+rs2[1]+rs2[2]+rs2[3];
    float mu  = ts/(float)DM_;
    float var = ts2/(float)DM_ - mu*mu;
    stats[0] = mu; stats[1] = rsqrtf(var + 1e-5f);
  }
  __syncthreads();
  float mu = stats[0], rstd = stats[1];
  #pragma unroll
  for (int j=0;j<4;j++) {
    int n = threadIdx.x + j*256;
    out[(size_t)m*DM_ + n] = (v[j]-mu)*rstd*gma[n] + bta[n];
  }
}

extern "C" void kernel_launch(void* const* d_in, const int* in_sizes, int n_in,
                              void* d_out, int out_size, void* d_ws, size_t ws_size,
                              hipStream_t stream)
{
  const float* x       = (const float*)d_in[0];
  const float* in_w    = (const float*)d_in[1];
  const float* conv_w  = (const float*)d_in[2];
  const float* conv_b  = (const float*)d_in[3];
  const float* A_log   = (const float*)d_in[4];
  const float* Dp      = (const float*)d_in[5];
  const float* xproj_w = (const float*)d_in[6];
  const float* dt_w    = (const float*)d_in[7];
  const float* dt_b    = (const float*)d_in[8];
  const float* f_re    = (const float*)d_in[9];
  const float* f_im    = (const float*)d_in[10];
  const float* s_dec   = (const float*)d_in[11];
  const float* fus_w   = (const float*)d_in[12];
  const float* fus_b   = (const float*)d_in[13];
  const float* out_w   = (const float*)d_in[14];
  const float* ln_g    = (const float*)d_in[15];
  const float* ln_b    = (const float*)d_in[16];
  float* out = (float*)d_out;

  // ---- workspace carve (fp32 region then bf16 region), ~138 MB total ----
  float* ws    = (float*)d_ws;
  float* xz    = ws;                       // 8388608  (M x 4096)
  float* xconv = xz    + 8388608;          // 4194304  (M x 2048), reused as outp
  float* xdbc  = xconv + 4194304;          // 81920    (M x 40)
  float* Pq    = xdbc  + 81920;            // 4194304  (B*NCH*INNER x 32), holds h_in too
  u16* ub      = (u16*)(Pq + 4194304);
  u16* xb      = ub;                       // 2097152   x bf16
  u16* inwb    = xb    + 2097152;          // 4194304   in_w bf16
  u16* fuswb   = inwb  + 4194304;          // 8388608   fus_w bf16
  u16* outwb   = fuswb + 8388608;          // 2097152   out_w bf16
  u16* xt      = outwb + 2097152;          // 4194304   x_inner^T bf16; reused as ycomb
  u16* Wb      = xt    + 4194304;          // 1179648   Wdft then Winv
  u16* XFb     = Wb    + 1179648;          // 4718592   (MD x NFP) bf16
  u16* ycat    = XFb   + 4718592;          // 8388608   (M x 4096) bf16
  u16* ycomb   = xt;
  float* outp  = xconv;
  float* part  = (float*)ycat;             // 2.6M floats, dead before scan3 writes ycat

  // 0. convert GEMM operands to bf16 (xb,inwb,fuswb,outwb are contiguous)
  cvt4_k<<<CVT_NT/1024, 256, 0, stream>>>(x, in_w, fus_w, out_w, xb);

  // 1. xz = x @ in_proj_w^T (2048 x 4096 x 1024); epilogue also writes xt (bf16 transposed)
  //    128x64 tile: grid 1024 blocks (was 512 at 128x128) + deep pipeline
  mgemm_k<128,64,5><<<dim3(4096/64, M_/128), 256, 0, stream>>>(
      xb, inwb, xz, 1024, 4096, nullptr, xt, nullptr, nullptr);
  // 2. depthwise conv + silu (8 l per thread)
  conv_silu_k<<<(M_*INNER_/8)/256, 256, 0, stream>>>(xz, conv_w, conv_b, xconv);
  // 3. x_dbc = x_conv @ x_proj_w^T  (2048 x 40 x 2048) split-K fp32
  xproj_k<<<dim3(SK_, M_/256), 256, 0, stream>>>(xconv, xproj_w, part);
  xpred_k<<<(M_*40)/256, 256, 0, stream>>>(part, xdbc);
  // 4-6. chunked SSM scan -> y_cat[:, :2048] (bf16)
  scan1_k<<<(B_*NCH_*INNER_)/256, 256, 0, stream>>>(xdbc, xconv, A_log, dt_w, dt_b, Pq);
  scan2_k<<<(B_*INNER_*STATE_)/256, 256, 0, stream>>>(Pq);
  scan3_k<<<(B_*NCH_*INNER_)/256, 256, 0, stream>>>(xdbc, xconv, A_log, dt_w, dt_b, Dp, Pq, ycat);
  // 7. forward DFT + fused spectral filter: XFb = filt(xt @ Wdft), 576 blocks
  genWdftb_k<<<(NFP_*1024)/256, 256, 0, stream>>>(Wb);
  mgemm_k<128,64,3><<<dim3(NFP_/64, MD_/128), 256, 0, stream>>>(
      xt, Wb, XFb, 1024, NFP_, f_re, nullptr, s_dec, f_im);
  // 8. inverse DFT (4096 x 1024 x 1152); epilogue writes transposed into ycat[:,2048:]
  genWinvb_k<<<(NFP_*1024)/256, 256, 0, stream>>>(Wb);
  mgemm_k<128,64,6><<<dim3(1024/64, MD_/128), 256, 0, stream>>>(
      XFb, Wb, ycat, NFP_, 0, nullptr, nullptr, nullptr, nullptr);
  // 9. fusion GEMM + gate epilogue (2048 x 2048 x 4096) -> ycomb bf16, 512 blocks
  mgemm_k<128,64,1><<<dim3(2048/64, M_/128), 256, 0, stream>>>(
      ycat, fuswb, ycomb, 4096, 2048, fus_b, ycat, xz, nullptr);
  // 10. out proj + residual (2048 x 1024 x 2048) -> fp32, 512 blocks
  mgemm_k<64,64,2><<<dim3(1024/64, M_/64), 128, 0, stream>>>(
      ycomb, outwb, outp, 2048, 1024, nullptr, nullptr, x, nullptr);
  // 11. layernorm -> d_out
  ln_k<<<M_, 256, 0, stream>>>(outp, ln_g, ln_b, out);
}

// Round 2
// 412.813 us; speedup vs baseline: 1.0687x; 1.0687x over previous
//
#include <hip/hip_runtime.h>
#include <math.h>

#define B_ 2
#define L_ 1024
#define DM_ 1024
#define STATE_ 16
#define CONV_ 4
#define DTR_ 8
#define INNER_ 2048
#define M_ (B_*L_)        /* 2048 rows (b,l) */
#define MD_ (B_*INNER_)   /* 4096 rows (b,c) */
#define NFFT_ 513
#define NFP_ 1152         /* 2*513=1026 padded to multiple of 128 */
#define NCH_ 32
#define CHL_ 32
#define SK_ 32            /* x_proj split-K factor */
#define KSL_ (2048/SK_)   /* 64 */

typedef unsigned short u16;
typedef __attribute__((ext_vector_type(8))) short short8;
typedef __attribute__((ext_vector_type(8))) __bf16 bf16x8;
typedef __attribute__((ext_vector_type(4))) float f32x4;

__device__ __forceinline__ float frcp_(float x) { return __builtin_amdgcn_rcpf(x); }
__device__ __forceinline__ float fexp_(float x) { return __expf(x); }
__device__ __forceinline__ float fsigm_(float x) { return frcp_(1.f + __expf(-x)); }
__device__ __forceinline__ float fsilu_(float x) { return x * frcp_(1.f + __expf(-x)); }
__device__ __forceinline__ float fsoftplus_(float v) {
  return (v > 20.f) ? v : __logf(1.f + __expf(v));
}
__device__ __forceinline__ u16 f2bf(float f) {
  union { float f; unsigned u; } v; v.f = f;
  unsigned r = v.u + 0x7fffu + ((v.u >> 16) & 1u);
  return (u16)(r >> 16);
}
__device__ __forceinline__ float bf2f(u16 h) {
  union { unsigned u; float f; } v; v.u = ((unsigned)h) << 16;
  return v.f;
}
__device__ __forceinline__ void gload16(const void* g, void* l) {
  __builtin_amdgcn_global_load_lds(
      (const __attribute__((address_space(1))) unsigned*)g,
      (__attribute__((address_space(3))) unsigned*)l, 16, 0, 0);
}
__device__ __forceinline__ f32x4 mfma_bf16(short8 a, short8 b, f32x4 c) {
  return __builtin_amdgcn_mfma_f32_16x16x32_bf16(
      __builtin_bit_cast(bf16x8, a), __builtin_bit_cast(bf16x8, b), c, 0, 0, 0);
}

// ---------------- fp32 -> bf16 conversion (4 sources, contiguous dst) -------
#define CVT_N0 2097152
#define CVT_N1 6291456
#define CVT_N2 14680064
#define CVT_NT 16777216
__global__ __launch_bounds__(256) void cvt4_k(
    const float* __restrict__ s0, const float* __restrict__ s1,
    const float* __restrict__ s2, const float* __restrict__ s3,
    u16* __restrict__ out)
{
  int i = (blockIdx.x*256 + threadIdx.x) * 4;
  const float* src; int off;
  if (i < CVT_N0)      { src = s0; off = 0; }
  else if (i < CVT_N1) { src = s1; off = CVT_N0; }
  else if (i < CVT_N2) { src = s2; off = CVT_N1; }
  else                 { src = s3; off = CVT_N2; }
  float4 v = *(const float4*)(src + (i - off));
  ushort4 o;
  o.x = f2bf(v.x); o.y = f2bf(v.y); o.z = f2bf(v.z); o.w = f2bf(v.w);
  *(ushort4*)(out + i) = o;
}

// ---------------- bf16 MFMA GEMM (templated tile, double-buffered) ----------
// C[m,n] = sum_k A[m,k]*Bt[n,k].  A: M x K bf16, Bt: N x K bf16, K%64==0.
// Wave sub-tile 64x32 (acc 4x2); waves = (TM/64)*(TN/32).
// 1-D grid + bijective XCD-chunked remap (T1): blocks with bid%8 (= XCD id)
// get a CONTIGUOUS logical tile range, so each XCD's L2 sees a compact
// footprint instead of fetching the full shared panel 8x.
// YCH=1: y-outer chunk (per-XCD = few M-rows x all N-cols; dedups a large A
//        when B is small/L2-resident, e.g. DFT GEMMs).
// YCH=0: x-outer chunk (per-XCD = few N-cols x all M-rows).
// EPI: 0 plain f32; 1 fusion gate (bf16); 2 residual add (f32);
//      3 spectral filter (bf16); 5 in_proj (f32 + transposed bf16 xt);
//      6 inv-DFT (bf16 transposed into ycat).
template<int TM, int TN, int EPI, int YCH>
__global__ __launch_bounds__((TM/64)*(TN/32)*64) void mgemm_k(
    const u16* __restrict__ Ab, const u16* __restrict__ Bb,
    void* __restrict__ Cout, int K, int ldc,
    const float* __restrict__ aux0, u16* __restrict__ aux1,
    const float* __restrict__ aux2, const float* __restrict__ aux3,
    int gx, int gy)
{
  constexpr int WN   = TN/32;
  constexpr int NW   = (TM/64)*WN;
  constexpr int NTHR = NW*64;
  __shared__ __align__(16) u16 As[2][TM*64];
  __shared__ __align__(16) u16 Bs[2][TN*64];
  const int t = threadIdx.x;
  const int lane = t & 63;
  const int w = t >> 6;
  const int wm = w / WN, wn = w % WN;

  // XCD-chunked bijective remap (nwg % 8 == 0 at every call site)
  const int nwg = gx * gy;
  const int bid = blockIdx.x;
  const int lid = (bid & 7) * (nwg >> 3) + (bid >> 3);
  int bx, by;
  if (YCH) { by = lid / gx; bx = lid - by*gx; }
  else     { bx = lid / gy; by = lid - bx*gy; }
  const int M0 = by * TM, N0 = bx * TN;

  f32x4 acc[4][2] = {};

  auto stage = [&](int buf, int k0) {
    #pragma unroll
    for (int q = 0; q < TM*8/NTHR; q++) {
      int u = q*NTHR + t;
      int row = u >> 3, gpr = u & 7;
      int grp = gpr ^ (row & 7);        // XOR swizzle
      gload16(Ab + (size_t)(M0+row)*K + k0 + grp*8, &As[buf][u*8]);
    }
    #pragma unroll
    for (int q = 0; q < TN*8/NTHR; q++) {
      int u = q*NTHR + t;
      int row = u >> 3, gpr = u & 7;
      int grp = gpr ^ (row & 7);
      gload16(Bb + (size_t)(N0+row)*K + k0 + grp*8, &Bs[buf][u*8]);
    }
  };

  stage(0, 0);
  const int nk = K >> 6;
  for (int ks = 0; ks < nk; ks++) {
    const int buf = ks & 1;
    __syncthreads();                    // drain stage(buf); protect buf^1 overwrite
    if (ks + 1 < nk) stage(buf ^ 1, (ks + 1) << 6);
    const u16* Asb = As[buf];
    const u16* Bsb = Bs[buf];
    #pragma unroll
    for (int kk = 0; kk < 2; kk++) {
      const int quad = lane >> 4;
      const int grp = kk*4 + quad;
      short8 af[4], bfr[2];
      #pragma unroll
      for (int i = 0; i < 4; i++) {
        int row = wm*64 + i*16 + (lane & 15);
        af[i] = *(const short8*)&Asb[(row*8 + (grp ^ (row & 7)))*8];
      }
      #pragma unroll
      for (int j = 0; j < 2; j++) {
        int row = wn*32 + j*16 + (lane & 15);
        bfr[j] = *(const short8*)&Bsb[(row*8 + (grp ^ (row & 7)))*8];
      }
      #pragma unroll
      for (int i = 0; i < 4; i++)
        #pragma unroll
        for (int j = 0; j < 2; j++)
          acc[i][j] = mfma_bf16(af[i], bfr[j], acc[i][j]);
    }
  }

  // C/D layout: col = lane&15, row = (lane>>4)*4 + r
  #pragma unroll
  for (int i = 0; i < 4; i++) {
    int mbase = M0 + wm*64 + i*16 + (lane >> 4)*4;
    #pragma unroll
    for (int j = 0; j < 2; j++) {
      int n = N0 + wn*32 + j*16 + (lane & 15);
      #pragma unroll
      for (int r = 0; r < 4; r++) {
        int m = mbase + r;
        float v = acc[i][j][r];
        if (EPI == 0) {
          ((float*)Cout)[(size_t)m*ldc + n] = v;
        } else if (EPI == 1) {          // fusion gate
          float g  = fsigm_(v + aux0[n]);
          float ys = bf2f(aux1[(size_t)m*4096 + n]);
          float yp = bf2f(aux1[(size_t)m*4096 + 2048 + n]);
          float z  = aux2[(size_t)m*4096 + 2048 + n];
          ((u16*)Cout)[(size_t)m*ldc + n] = f2bf((g*ys + (1.f-g)*yp)*fsilu_(z));
        } else if (EPI == 2) {          // residual add
          ((float*)Cout)[(size_t)m*ldc + n] = v + aux2[(size_t)m*ldc + n];
        } else if (EPI == 3) {          // spectral filter, complex pair via shfl
          float pv = __shfl_xor(v, 1, 64);
          int f = n >> 1;
          float outv = 0.f;
          if (f < NFFT_) {
            int c = m & (INNER_-1);
            float d  = fexp_(-aux2[c] * (float)f * (1.f/512.f));
            float wr = aux0[c*NFFT_+f]*d, wi = aux3[c*NFFT_+f]*d;
            float a = (n & 1) ? pv : v;
            float b = (n & 1) ? v : pv;
            outv = (n & 1) ? (a*wi + b*wr) : (a*wr - b*wi);
          }
          ((u16*)Cout)[(size_t)m*ldc + n] = f2bf(outv);
        } else if (EPI == 5) {          // in_proj: xz f32 + transposed bf16 xt
          ((float*)Cout)[(size_t)m*ldc + n] = v;
          if (n < 2048) {
            int b2 = m >> 10, l2 = m & 1023;
            aux1[((size_t)(b2*2048 + n) << 10) + l2] = f2bf(v);
          }
        } else {                        // 6: inv-DFT transposed into ycat
          int b2 = m >> 11, c2 = m & (INNER_-1);
          ((u16*)Cout)[((size_t)((b2 << 10) + n) << 12) + 2048 + c2] = f2bf(v);
        }
      }
    }
  }
}

// ---------------- x_proj split-K: part[sk][m][40] = xconv[m, sk*64:+64] @ W^T ----
__global__ __launch_bounds__(256) void xproj_k(
    const float* __restrict__ xconv, const float* __restrict__ W,
    float* __restrict__ part)
{
  __shared__ float Bs[40][KSL_+4];
  const int sk = blockIdx.x, mt = blockIdx.y;
  const int k0 = sk*KSL_;
  for (int i = threadIdx.x; i < 40*KSL_; i += 256) {
    int n = i >> 6, k = i & (KSL_-1);
    Bs[n][k] = W[(size_t)n*2048 + k0 + k];
  }
  __syncthreads();
  const int m = mt*256 + threadIdx.x;
  const float* arow = xconv + (size_t)m*2048 + k0;
  float acc[40];
  #pragma unroll
  for (int j=0;j<40;j++) acc[j]=0.f;
  for (int k = 0; k < KSL_; k += 4) {
    float4 a = *(const float4*)(arow + k);
    #pragma unroll
    for (int j = 0; j < 40; j++) {
      float4 b = *(const float4*)&Bs[j][k];
      acc[j] += a.x*b.x + a.y*b.y + a.z*b.z + a.w*b.w;
    }
  }
  float* o = part + ((size_t)sk*M_ + m)*40;
  #pragma unroll
  for (int j = 0; j < 10; j++)
    *(float4*)(o + j*4) = make_float4(acc[j*4], acc[j*4+1], acc[j*4+2], acc[j*4+3]);
}

__global__ __launch_bounds__(256) void xpred_k(const float* __restrict__ part,
                                               float* __restrict__ xdbc)
{
  int i = blockIdx.x*256 + threadIdx.x;   // 81920 total
  float s = 0.f;
  #pragma unroll
  for (int sk = 0; sk < SK_; sk++) s += part[(size_t)sk*81920 + i];
  xdbc[i] = s;
}

// ---------------- depthwise causal conv(4) + silu, 8 l per thread ----------
__global__ __launch_bounds__(256) void conv_silu_k(
    const float* __restrict__ xz, const float* __restrict__ cw,
    const float* __restrict__ cb, float* __restrict__ xc)
{
  int idx = blockIdx.x*256 + threadIdx.x;   // 524288 total
  int c = idx & (INNER_-1);
  int g = idx >> 11;                        // 0..255
  int b = g >> 7;
  int lb = (g & 127) * 8;
  float w0=cw[c*4+0], w1=cw[c*4+1], w2=cw[c*4+2], w3=cw[c*4+3];
  float bias = cb[c];
  float v[11];
  #pragma unroll
  for (int j = 0; j < 11; j++) {
    int l = lb - 3 + j;
    v[j] = (l >= 0) ? xz[((size_t)((b << 10) + l))*4096 + c] : 0.f;
  }
  #pragma unroll
  for (int j = 0; j < 8; j++) {
    float s = bias + w0*v[j] + w1*v[j+1] + w2*v[j+2] + w3*v[j+3];
    xc[((size_t)((b << 10) + lb + j))*INNER_ + c] = fsilu_(s);
  }
}

// ---------------- SSM chunked scan (prefetched) ----------------
// Pq layout per (b,ch,e): [0..15] = P (chunk transfer), [16..31] = q, then
// scan2 overwrites q-slot with h_in for that chunk.
__global__ __launch_bounds__(256) void scan1_k(
    const float* __restrict__ xdbc, const float* __restrict__ xconv,
    const float* __restrict__ A_log, const float* __restrict__ dtw,
    const float* __restrict__ dtb, float* __restrict__ Pq)
{
  int idx = blockIdx.x*256 + threadIdx.x;   // (b*NCH+ch)*INNER + e
  int e  = idx & (INNER_-1);
  int bc = idx >> 11;
  int ch = bc & (NCH_-1);
  int b  = bc >> 5;
  float A[STATE_];
  #pragma unroll
  for (int s=0;s<STATE_;s++) A[s] = -fexp_(A_log[e*STATE_+s]);
  float w[DTR_];
  #pragma unroll
  for (int r=0;r<DTR_;r++) w[r] = dtw[e*DTR_+r];
  float bias = dtb[e];
  float h[STATE_] = {};
  float sdt = 0.f;
  int mbase = b*L_ + ch*CHL_;
  // current-step inputs
  float dtx[DTR_], Bv[STATE_], xcv;
  {
    const float* row = xdbc + (size_t)mbase*40;
    #pragma unroll
    for (int r=0;r<DTR_;r++) dtx[r] = row[r];
    #pragma unroll
    for (int s=0;s<STATE_;s++) Bv[s] = row[8+s];
    xcv = xconv[(size_t)mbase*INNER_ + e];
  }
  for (int l=0;l<CHL_;l++) {
    float ndtx[DTR_], nBv[STATE_], nxcv = 0.f;
    if (l+1 < CHL_) {                 // prefetch next step
      const float* nrow = xdbc + (size_t)(mbase+l+1)*40;
      #pragma unroll
      for (int r=0;r<DTR_;r++) ndtx[r] = nrow[r];
      #pragma unroll
      for (int s=0;s<STATE_;s++) nBv[s] = nrow[8+s];
      nxcv = xconv[(size_t)(mbase+l+1)*INNER_ + e];
    } else {
      #pragma unroll
      for (int r=0;r<DTR_;r++) ndtx[r] = 0.f;
      #pragma unroll
      for (int s=0;s<STATE_;s++) nBv[s] = 0.f;
    }
    float v = bias;
    #pragma unroll
    for (int r=0;r<DTR_;r++) v += dtx[r]*w[r];
    float dt = fsoftplus_(v);
    sdt += dt;
    float dx = dt * xcv;
    #pragma unroll
    for (int s=0;s<STATE_;s++) {
      float dA = fexp_(dt*A[s]);
      h[s] = dA*h[s] + dx*Bv[s];
    }
    #pragma unroll
    for (int r=0;r<DTR_;r++) dtx[r] = ndtx[r];
    #pragma unroll
    for (int s=0;s<STATE_;s++) Bv[s] = nBv[s];
    xcv = nxcv;
  }
  float* o = Pq + (size_t)idx*32;
  #pragma unroll
  for (int s=0;s<STATE_;s++) { o[s] = fexp_(A[s]*sdt); o[16+s] = h[s]; }
}

// combine chunks, parallel over (b,e,s); h_in written into the q slot
__global__ __launch_bounds__(256) void scan2_k(float* __restrict__ Pq)
{
  int idx = blockIdx.x*256 + threadIdx.x;   // b*(INNER*16) + e*16 + s ; 65536
  int s = idx & 15;
  int e = (idx >> 4) & (INNER_-1);
  int b = idx >> 15;
  float h = 0.f;
  for (int ch = 0; ch < NCH_; ch++) {
    size_t base = ((size_t)(b*NCH_+ch)*INNER_ + e)*32;
    float p = Pq[base + s];
    float q = Pq[base + 16 + s];
    Pq[base + 16 + s] = h;
    h = p*h + q;
  }
}

__global__ __launch_bounds__(256) void scan3_k(
    const float* __restrict__ xdbc, const float* __restrict__ xconv,
    const float* __restrict__ A_log, const float* __restrict__ dtw,
    const float* __restrict__ dtb, const float* __restrict__ Dp,
    const float* __restrict__ Pq, u16* __restrict__ ycat)
{
  int idx = blockIdx.x*256 + threadIdx.x;
  int e  = idx & (INNER_-1);
  int bc = idx >> 11;
  int ch = bc & (NCH_-1);
  int b  = bc >> 5;
  float A[STATE_];
  #pragma unroll
  for (int s=0;s<STATE_;s++) A[s] = -fexp_(A_log[e*STATE_+s]);
  float w[DTR_];
  #pragma unroll
  for (int r=0;r<DTR_;r++) w[r] = dtw[e*DTR_+r];
  float bias = dtb[e];
  float Dv = Dp[e];
  float h[STATE_];
  const float* hi = Pq + (size_t)idx*32 + 16;
  #pragma unroll
  for (int s=0;s<STATE_;s++) h[s] = hi[s];
  int mbase = b*L_ + ch*CHL_;
  float dtx[DTR_], Bv[STATE_], Cv[STATE_], xcv;
  {
    const float* row = xdbc + (size_t)mbase*40;
    #pragma unroll
    for (int r=0;r<DTR_;r++) dtx[r] = row[r];
    #pragma unroll
    for (int s=0;s<STATE_;s++) { Bv[s] = row[8+s]; Cv[s] = row[24+s]; }
    xcv = xconv[(size_t)mbase*INNER_ + e];
  }
  for (int l=0;l<CHL_;l++) {
    float ndtx[DTR_], nBv[STATE_], nCv[STATE_], nxcv = 0.f;
    if (l+1 < CHL_) {
      const float* nrow = xdbc + (size_t)(mbase+l+1)*40;
      #pragma unroll
      for (int r=0;r<DTR_;r++) ndtx[r] = nrow[r];
      #pragma unroll
      for (int s=0;s<STATE_;s++) { nBv[s] = nrow[8+s]; nCv[s] = nrow[24+s]; }
      nxcv = xconv[(size_t)(mbase+l+1)*INNER_ + e];
    } else {
      #pragma unroll
      for (int r=0;r<DTR_;r++) ndtx[r] = 0.f;
      #pragma unroll
      for (int s=0;s<STATE_;s++) { nBv[s] = 0.f; nCv[s] = 0.f; }
    }
    float v = bias;
    #pragma unroll
    for (int r=0;r<DTR_;r++) v += dtx[r]*w[r];
    float dt = fsoftplus_(v);
    float dx = dt * xcv;
    float y = 0.f;
    #pragma unroll
    for (int s=0;s<STATE_;s++) {
      float dA = fexp_(dt*A[s]);
      h[s] = dA*h[s] + dx*Bv[s];
      y += h[s]*Cv[s];
    }
    ycat[(size_t)(mbase+l)*4096 + e] = f2bf(y + xcv*Dv);
    #pragma unroll
    for (int r=0;r<DTR_;r++) dtx[r] = ndtx[r];
    #pragma unroll
    for (int s=0;s<STATE_;s++) { Bv[s] = nBv[s]; Cv[s] = nCv[s]; }
    xcv = nxcv;
  }
}

// ---------------- DFT matrix generation (bf16, K-contiguous) ----------------
__global__ __launch_bounds__(256) void genWdftb_k(u16* __restrict__ W) {
  int idx = blockIdx.x*256 + threadIdx.x;  // col*1024 + l ; col < NFP_
  int l = idx & (L_-1);
  int col = idx >> 10;
  float v = 0.f;
  int f = col >> 1;
  if (f < NFFT_) {
    int ph = (l*f) & (L_-1);
    float th = (float)ph * (6.283185307179586f / (float)L_);
    v = (col & 1) ? -__sinf(th) : __cosf(th);
  }
  W[idx] = f2bf(v);
}

__global__ __launch_bounds__(256) void genWinvb_k(u16* __restrict__ W) {
  int idx = blockIdx.x*256 + threadIdx.x;  // l*NFP_ + r
  int r = idx % NFP_;
  int l = idx / NFP_;
  int f = r >> 1;
  float v = 0.f;
  if (f < NFFT_) {
    bool edge = (f == 0) || (f == 512);
    float sc = (edge ? 1.f : 2.f) / (float)L_;
    int ph = (f*l) & (L_-1);
    float th = (float)ph * (6.283185307179586f / (float)L_);
    if (r & 1) v = edge ? 0.f : -sc*__sinf(th);
    else       v = sc*__cosf(th);
  }
  W[idx] = f2bf(v);
}

// ---------------- layernorm ----------------
__global__ __launch_bounds__(256) void ln_k(const float* __restrict__ inp,
    const float* __restrict__ gma, const float* __restrict__ bta,
    float* __restrict__ out)
{
  int m = blockIdx.x;
  const float* row = inp + (size_t)m*DM_;
  float s=0.f, s2=0.f;
  float v[4];
  #pragma unroll
  for (int j=0;j<4;j++) {
    v[j] = row[threadIdx.x + j*256];
    s += v[j]; s2 += v[j]*v[j];
  }
  #pragma unroll
  for (int off=32; off>=1; off>>=1) {
    s  += __shfl_down(s, off);
    s2 += __shfl_down(s2, off);
  }
  __shared__ float rs[4], rs2[4], stats[2];
  int wid = threadIdx.x >> 6;
  if ((threadIdx.x & 63) == 0) { rs[wid]=s; rs2[wid]=s2; }
  __syncthreads();
  if (threadIdx.x == 0) {
    float ts  = rs[0]+rs[1]+rs[2]+rs[3];
    float ts2 = rs2[0]+rs2[1]+rs2[2]+rs2[3];
    float mu  = ts/(float)DM_;
    float var = ts2/(float)DM_ - mu*mu;
    stats[0] = mu; stats[1] = rsqrtf(var + 1e-5f);
  }
  __syncthreads();
  float mu = stats[0], rstd = stats[1];
  #pragma unroll
  for (int j=0;j<4;j++) {
    int n = threadIdx.x + j*256;
    out[(size_t)m*DM_ + n] = (v[j]-mu)*rstd*gma[n] + bta[n];
  }
}

extern "C" void kernel_launch(void* const* d_in, const int* in_sizes, int n_in,
                              void* d_out, int out_size, void* d_ws, size_t ws_size,
                              hipStream_t stream)
{
  const float* x       = (const float*)d_in[0];
  const float* in_w    = (const float*)d_in[1];
  const float* conv_w  = (const float*)d_in[2];
  const float* conv_b  = (const float*)d_in[3];
  const float* A_log   = (const float*)d_in[4];
  const float* Dp      = (const float*)d_in[5];
  const float* xproj_w = (const float*)d_in[6];
  const float* dt_w    = (const float*)d_in[7];
  const float* dt_b    = (const float*)d_in[8];
  const float* f_re    = (const float*)d_in[9];
  const float* f_im    = (const float*)d_in[10];
  const float* s_dec   = (const float*)d_in[11];
  const float* fus_w   = (const float*)d_in[12];
  const float* fus_b   = (const float*)d_in[13];
  const float* out_w   = (const float*)d_in[14];
  const float* ln_g    = (const float*)d_in[15];
  const float* ln_b    = (const float*)d_in[16];
  float* out = (float*)d_out;

  // ---- workspace carve (fp32 region then bf16 region), ~138 MB total ----
  float* ws    = (float*)d_ws;
  float* xz    = ws;                       // 8388608  (M x 4096)
  float* xconv = xz    + 8388608;          // 4194304  (M x 2048), reused as outp
  float* xdbc  = xconv + 4194304;          // 81920    (M x 40)
  float* Pq    = xdbc  + 81920;            // 4194304  (B*NCH*INNER x 32), holds h_in too
  u16* ub      = (u16*)(Pq + 4194304);
  u16* xb      = ub;                       // 2097152   x bf16
  u16* inwb    = xb    + 2097152;          // 4194304   in_w bf16
  u16* fuswb   = inwb  + 4194304;          // 8388608   fus_w bf16
  u16* outwb   = fuswb + 8388608;          // 2097152   out_w bf16
  u16* xt      = outwb + 2097152;          // 4194304   x_inner^T bf16; reused as ycomb
  u16* Wb      = xt    + 4194304;          // 1179648   Wdft then Winv
  u16* XFb     = Wb    + 1179648;          // 4718592   (MD x NFP) bf16
  u16* ycat    = XFb   + 4718592;          // 8388608   (M x 4096) bf16
  u16* ycomb   = xt;
  float* outp  = xconv;
  float* part  = (float*)ycat;             // 2.6M floats, dead before scan3 writes ycat

  // 0. convert GEMM operands to bf16 (xb,inwb,fuswb,outwb are contiguous)
  cvt4_k<<<CVT_NT/1024, 256, 0, stream>>>(x, in_w, fus_w, out_w, xb);

  // 1. xz = x @ in_proj_w^T (2048 x 4096 x 1024); epilogue also writes xt (bf16 transposed)
  //    x-outer chunk: per-XCD footprint A 4MB + B 1MB
  mgemm_k<128,128,5,0><<<512, 512, 0, stream>>>(
      xb, inwb, xz, 1024, 4096, nullptr, xt, nullptr, nullptr, 32, 16);
  // 2. depthwise conv + silu (8 l per thread)
  conv_silu_k<<<(M_*INNER_/8)/256, 256, 0, stream>>>(xz, conv_w, conv_b, xconv);
  // 3. x_dbc = x_conv @ x_proj_w^T  (2048 x 40 x 2048) split-K fp32
  xproj_k<<<dim3(SK_, M_/256), 256, 0, stream>>>(xconv, xproj_w, part);
  xpred_k<<<(M_*40)/256, 256, 0, stream>>>(part, xdbc);
  // 4-6. chunked SSM scan -> y_cat[:, :2048] (bf16)
  scan1_k<<<(B_*NCH_*INNER_)/256, 256, 0, stream>>>(xdbc, xconv, A_log, dt_w, dt_b, Pq);
  scan2_k<<<(B_*INNER_*STATE_)/256, 256, 0, stream>>>(Pq);
  scan3_k<<<(B_*NCH_*INNER_)/256, 256, 0, stream>>>(xdbc, xconv, A_log, dt_w, dt_b, Dp, Pq, ycat);
  // 7. forward DFT + fused spectral filter: XFb = filt(xt @ Wdft)
  //    y-outer chunk: per-XCD = 4 M-rows x all N; A slice 1MB + B 2.25MB (L2-fits)
  genWdftb_k<<<(NFP_*1024)/256, 256, 0, stream>>>(Wb);
  mgemm_k<128,64,3,1><<<576, 256, 0, stream>>>(
      xt, Wb, XFb, 1024, NFP_, f_re, nullptr, s_dec, f_im, 18, 32);
  // 8. inverse DFT (4096 x 1024 x 1152); epilogue writes transposed into ycat[:,2048:]
  //    y-outer chunk: per-XCD A slice 0.6MB + B 2.25MB
  genWinvb_k<<<(NFP_*1024)/256, 256, 0, stream>>>(Wb);
  mgemm_k<128,64,6,1><<<512, 256, 0, stream>>>(
      XFb, Wb, ycat, NFP_, 0, nullptr, nullptr, nullptr, nullptr, 16, 32);
  // 9. fusion GEMM + gate epilogue (2048 x 2048 x 4096) -> ycomb bf16
  //    x-outer chunk (natural-equivalent; K=4096 panels too large to dedup)
  mgemm_k<128,64,1,0><<<512, 256, 0, stream>>>(
      ycat, fuswb, ycomb, 4096, 2048, fus_b, ycat, xz, nullptr, 32, 16);
  // 10. out proj + residual (2048 x 1024 x 2048) -> fp32; y-outer chunk
  mgemm_k<64,64,2,1><<<512, 128, 0, stream>>>(
      ycomb, outwb, outp, 2048, 1024, nullptr, nullptr, x, nullptr, 16, 32);
  // 11. layernorm -> d_out
  ln_k<<<M_, 256, 0, stream>>>(outp, ln_g, ln_b, out);
}

// Round 4
// 403.584 us; speedup vs baseline: 1.0932x; 1.0229x over previous
//
#include <hip/hip_runtime.h>
#include <math.h>

#define B_ 2
#define L_ 1024
#define DM_ 1024
#define STATE_ 16
#define CONV_ 4
#define DTR_ 8
#define INNER_ 2048
#define M_ (B_*L_)        /* 2048 rows (b,l) */
#define MD_ (B_*INNER_)   /* 4096 rows (b,c) */
#define NFFT_ 513
#define NFP_ 1088         /* 2*513=1026 padded to 17*64 */
#define NCH_ 32
#define CHL_ 32
#define SK_ 16            /* x_proj split-K factor (part fits in dead inwb) */
#define KSL_ (2048/SK_)   /* 128 */

typedef unsigned short u16;
typedef __attribute__((ext_vector_type(8))) short short8;
typedef __attribute__((ext_vector_type(8))) __bf16 bf16x8;
typedef __attribute__((ext_vector_type(4))) float f32x4;

__device__ __forceinline__ float frcp_(float x) { return __builtin_amdgcn_rcpf(x); }
__device__ __forceinline__ float fexp_(float x) { return __expf(x); }
__device__ __forceinline__ float fsigm_(float x) { return frcp_(1.f + __expf(-x)); }
__device__ __forceinline__ float fsilu_(float x) { return x * frcp_(1.f + __expf(-x)); }
__device__ __forceinline__ float fsoftplus_(float v) {
  return (v > 20.f) ? v : __logf(1.f + __expf(v));
}
__device__ __forceinline__ u16 f2bf(float f) {
  union { float f; unsigned u; } v; v.f = f;
  unsigned r = v.u + 0x7fffu + ((v.u >> 16) & 1u);
  return (u16)(r >> 16);
}
__device__ __forceinline__ float bf2f(u16 h) {
  union { unsigned u; float f; } v; v.u = ((unsigned)h) << 16;
  return v.f;
}
__device__ __forceinline__ void gload16(const void* g, void* l) {
  __builtin_amdgcn_global_load_lds(
      (const __attribute__((address_space(1))) unsigned*)g,
      (__attribute__((address_space(3))) unsigned*)l, 16, 0, 0);
}
__device__ __forceinline__ f32x4 mfma_bf16(short8 a, short8 b, f32x4 c) {
  return __builtin_amdgcn_mfma_f32_16x16x32_bf16(
      __builtin_bit_cast(bf16x8, a), __builtin_bit_cast(bf16x8, b), c, 0, 0, 0);
}

// ---------------- fp32 -> bf16 conversion (4 sources, contiguous dst) -------
#define CVT_N0 2097152
#define CVT_N1 6291456
#define CVT_N2 14680064
#define CVT_NT 16777216
__global__ __launch_bounds__(256) void cvt4_k(
    const float* __restrict__ s0, const float* __restrict__ s1,
    const float* __restrict__ s2, const float* __restrict__ s3,
    u16* __restrict__ out)
{
  int i = (blockIdx.x*256 + threadIdx.x) * 4;
  const float* src; int off;
  if (i < CVT_N0)      { src = s0; off = 0; }
  else if (i < CVT_N1) { src = s1; off = CVT_N0; }
  else if (i < CVT_N2) { src = s2; off = CVT_N1; }
  else                 { src = s3; off = CVT_N2; }
  float4 v = *(const float4*)(src + (i - off));
  ushort4 o;
  o.x = f2bf(v.x); o.y = f2bf(v.y); o.z = f2bf(v.z); o.w = f2bf(v.w);
  *(ushort4*)(out + i) = o;
}

// ---------------- aux bodies (grid-fused into GEMM launches) ----------------
// depthwise causal conv(4) + silu, 8 l per thread; idx < M_*INNER_/8
__device__ __forceinline__ void conv_body(int idx, const float* __restrict__ xz,
    const float* __restrict__ cw, const float* __restrict__ cb,
    float* __restrict__ xc)
{
  int c = idx & (INNER_-1);
  int g = idx >> 11;                        // 0..255
  int b = g >> 7;
  int lb = (g & 127) * 8;
  float w0=cw[c*4+0], w1=cw[c*4+1], w2=cw[c*4+2], w3=cw[c*4+3];
  float bias = cb[c];
  float v[11];
  #pragma unroll
  for (int j = 0; j < 11; j++) {
    int l = lb - 3 + j;
    v[j] = (l >= 0) ? xz[((size_t)((b << 10) + l))*4096 + c] : 0.f;
  }
  #pragma unroll
  for (int j = 0; j < 8; j++) {
    float s = bias + w0*v[j] + w1*v[j+1] + w2*v[j+2] + w3*v[j+3];
    xc[((size_t)((b << 10) + lb + j))*INNER_ + c] = fsilu_(s);
  }
}

// DFT matrix (bf16, K-contiguous): W[col*1024 + l], col < NFP_
__device__ __forceinline__ void genWdft_body(int idx, u16* __restrict__ W)
{
  int l = idx & (L_-1);
  int col = idx >> 10;
  float v = 0.f;
  int f = col >> 1;
  if (f < NFFT_) {
    int ph = (l*f) & (L_-1);
    float th = (float)ph * (6.283185307179586f / (float)L_);
    v = (col & 1) ? -__sinf(th) : __cosf(th);
  }
  W[idx] = f2bf(v);
}

// inverse-DFT matrix: W[l*NFP_ + r], l < 1024, r < NFP_
__device__ __forceinline__ void genWinv_body(int idx, u16* __restrict__ W)
{
  int r = idx % NFP_;
  int l = idx / NFP_;
  int f = r >> 1;
  float v = 0.f;
  if (f < NFFT_) {
    bool edge = (f == 0) || (f == 512);
    float sc = (edge ? 1.f : 2.f) / (float)L_;
    int ph = (f*l) & (L_-1);
    float th = (float)ph * (6.283185307179586f / (float)L_);
    if (r & 1) v = edge ? 0.f : -sc*__sinf(th);
    else       v = sc*__cosf(th);
  }
  W[idx] = f2bf(v);
}

// x_proj split-K slice: part[sk][m][40] = xconv[m, sk*KSL_:+KSL_] @ W^T
// eb in [0, SK_*(M_/256)): sk = eb&(SK_-1), mt = eb>>log2(SK_).
// lds: >=40*(KSL_+4)*4 = 21120 bytes scratch (borrows GEMM's As region).
__device__ __forceinline__ void xproj_body(int eb,
    const float* __restrict__ xconv, const float* __restrict__ W,
    float* __restrict__ part, void* lds)
{
  float (*Bs)[KSL_+4] = (float(*)[KSL_+4])lds;
  const int sk = eb & (SK_-1), mt = eb / SK_;
  const int k0 = sk*KSL_;
  for (int i = threadIdx.x; i < 40*KSL_; i += 256) {
    int n = i / KSL_, k = i & (KSL_-1);
    Bs[n][k] = W[(size_t)n*2048 + k0 + k];
  }
  __syncthreads();
  const int m = mt*256 + threadIdx.x;
  const float* arow = xconv + (size_t)m*2048 + k0;
  float acc[40];
  #pragma unroll
  for (int j=0;j<40;j++) acc[j]=0.f;
  for (int k = 0; k < KSL_; k += 4) {
    float4 a = *(const float4*)(arow + k);
    #pragma unroll
    for (int j = 0; j < 40; j++) {
      float4 b = *(const float4*)&Bs[j][k];
      acc[j] += a.x*b.x + a.y*b.y + a.z*b.z + a.w*b.w;
    }
  }
  float* o = part + ((size_t)sk*M_ + m)*40;
  #pragma unroll
  for (int j = 0; j < 10; j++)
    *(float4*)(o + j*4) = make_float4(acc[j*4], acc[j*4+1], acc[j*4+2], acc[j*4+3]);
}

// ---------------- bf16 MFMA GEMM (templated tile, double-buffered) ----------
// C[m,n] = sum_k A[m,k]*Bt[n,k].  A: M x K bf16, Bt: N x K bf16, K%64==0.
// Wave sub-tile 64x32 (acc 4x2); waves = (TM/64)*(TN/32).
// Blocks [0, gx*gy) run the GEMM (1-D grid, bijective XCD-chunked remap);
// blocks beyond run grid-fused aux work (AUX: 1 = genWdft; 2 = conv then
// genWinv; 3 = xproj) and return before touching the GEMM path. Aux work is
// independent of this launch's GEMM (deps point to earlier launches) and
// WRITES DISJOINT MEMORY from this launch's GEMM (audited per launch).
// EPI: 0 plain f32; 1 fusion gate (bf16); 2 residual add (f32);
//      3 spectral filter (bf16); 5 in_proj (f32 + transposed bf16 xt);
//      6 inv-DFT (bf16 transposed into ycat).
template<int TM, int TN, int EPI, int YCH, int AUX>
__global__ __launch_bounds__((TM/64)*(TN/32)*64) void mgemm_k(
    const u16* __restrict__ Ab, const u16* __restrict__ Bb,
    void* __restrict__ Cout, int K, int ldc,
    const float* __restrict__ aux0, u16* __restrict__ aux1,
    const float* __restrict__ aux2, const float* __restrict__ aux3,
    int gx, int gy,
    const float* __restrict__ ga, const float* __restrict__ gb,
    const float* __restrict__ gc, float* __restrict__ go,
    u16* __restrict__ gw)
{
  constexpr int WN   = TN/32;
  constexpr int NW   = (TM/64)*WN;
  constexpr int NTHR = NW*64;
  __shared__ __align__(16) u16 As[2][TM*64];
  __shared__ __align__(16) u16 Bs[2][TN*64];
  const int t = threadIdx.x;

  if constexpr (AUX != 0) {
    int eb = (int)blockIdx.x - gx*gy;
    if (eb >= 0) {
      if constexpr (AUX == 1) {              // genWdft (NFP_*1024 elems)
        genWdft_body(eb*NTHR + t, gw);
      } else if constexpr (AUX == 2) {       // conv (2048 blks) + genWinv
        if (eb < 2048) conv_body(eb*256 + t, ga, gb, gc, go);
        else           genWinv_body((eb - 2048)*256 + t, gw);
      } else {                               // 3: xproj (SK_*8 blks)
        xproj_body(eb, ga, gb, go, (void*)&As[0][0]);
      }
      return;
    }
  }

  const int lane = t & 63;
  const int w = t >> 6;
  const int wm = w / WN, wn = w % WN;

  // XCD-chunked bijective remap (nwg % 8 == 0 at every call site)
  const int nwg = gx * gy;
  const int bid = blockIdx.x;
  const int lid = (bid & 7) * (nwg >> 3) + (bid >> 3);
  int bx, by;
  if (YCH) { by = lid / gx; bx = lid - by*gx; }
  else     { bx = lid / gy; by = lid - bx*gy; }
  const int M0 = by * TM, N0 = bx * TN;

  f32x4 acc[4][2] = {};

  auto stage = [&](int buf, int k0) {
    #pragma unroll
    for (int q = 0; q < TM*8/NTHR; q++) {
      int u = q*NTHR + t;
      int row = u >> 3, gpr = u & 7;
      int grp = gpr ^ (row & 7);        // XOR swizzle
      gload16(Ab + (size_t)(M0+row)*K + k0 + grp*8, &As[buf][u*8]);
    }
    #pragma unroll
    for (int q = 0; q < TN*8/NTHR; q++) {
      int u = q*NTHR + t;
      int row = u >> 3, gpr = u & 7;
      int grp = gpr ^ (row & 7);
      gload16(Bb + (size_t)(N0+row)*K + k0 + grp*8, &Bs[buf][u*8]);
    }
  };

  stage(0, 0);
  const int nk = K >> 6;
  for (int ks = 0; ks < nk; ks++) {
    const int buf = ks & 1;
    __syncthreads();                    // drain stage(buf); protect buf^1 overwrite
    if (ks + 1 < nk) stage(buf ^ 1, (ks + 1) << 6);
    const u16* Asb = As[buf];
    const u16* Bsb = Bs[buf];
    #pragma unroll
    for (int kk = 0; kk < 2; kk++) {
      const int quad = lane >> 4;
      const int grp = kk*4 + quad;
      short8 af[4], bfr[2];
      #pragma unroll
      for (int i = 0; i < 4; i++) {
        int row = wm*64 + i*16 + (lane & 15);
        af[i] = *(const short8*)&Asb[(row*8 + (grp ^ (row & 7)))*8];
      }
      #pragma unroll
      for (int j = 0; j < 2; j++) {
        int row = wn*32 + j*16 + (lane & 15);
        bfr[j] = *(const short8*)&Bsb[(row*8 + (grp ^ (row & 7)))*8];
      }
      #pragma unroll
      for (int i = 0; i < 4; i++)
        #pragma unroll
        for (int j = 0; j < 2; j++)
          acc[i][j] = mfma_bf16(af[i], bfr[j], acc[i][j]);
    }
  }

  // C/D layout: col = lane&15, row = (lane>>4)*4 + r
  #pragma unroll
  for (int i = 0; i < 4; i++) {
    int mbase = M0 + wm*64 + i*16 + (lane >> 4)*4;
    #pragma unroll
    for (int j = 0; j < 2; j++) {
      int n = N0 + wn*32 + j*16 + (lane & 15);
      #pragma unroll
      for (int r = 0; r < 4; r++) {
        int m = mbase + r;
        float v = acc[i][j][r];
        if (EPI == 0) {
          ((float*)Cout)[(size_t)m*ldc + n] = v;
        } else if (EPI == 1) {          // fusion gate
          float g  = fsigm_(v + aux0[n]);
          float ys = bf2f(aux1[(size_t)m*4096 + n]);
          float yp = bf2f(aux1[(size_t)m*4096 + 2048 + n]);
          float z  = aux2[(size_t)m*4096 + 2048 + n];
          ((u16*)Cout)[(size_t)m*ldc + n] = f2bf((g*ys + (1.f-g)*yp)*fsilu_(z));
        } else if (EPI == 2) {          // residual add
          ((float*)Cout)[(size_t)m*ldc + n] = v + aux2[(size_t)m*ldc + n];
        } else if (EPI == 3) {          // spectral filter, complex pair via shfl
          float pv = __shfl_xor(v, 1, 64);
          int f = n >> 1;
          float outv = 0.f;
          if (f < NFFT_) {
            int c = m & (INNER_-1);
            float d  = fexp_(-aux2[c] * (float)f * (1.f/512.f));
            float wr = aux0[c*NFFT_+f]*d, wi = aux3[c*NFFT_+f]*d;
            float a = (n & 1) ? pv : v;
            float b = (n & 1) ? v : pv;
            outv = (n & 1) ? (a*wi + b*wr) : (a*wr - b*wi);
          }
          ((u16*)Cout)[(size_t)m*ldc + n] = f2bf(outv);
        } else if (EPI == 5) {          // in_proj: xz f32 + transposed bf16 xt
          ((float*)Cout)[(size_t)m*ldc + n] = v;
          if (n < 2048) {
            int b2 = m >> 10, l2 = m & 1023;
            aux1[((size_t)(b2*2048 + n) << 10) + l2] = f2bf(v);
          }
        } else {                        // 6: inv-DFT transposed into ycat
          int b2 = m >> 11, c2 = m & (INNER_-1);
          ((u16*)Cout)[((size_t)((b2 << 10) + n) << 12) + 2048 + c2] = f2bf(v);
        }
      }
    }
  }
}

__global__ __launch_bounds__(256) void xpred_k(const float* __restrict__ part,
                                               float* __restrict__ xdbc)
{
  int i = blockIdx.x*256 + threadIdx.x;   // 81920 total
  float s = 0.f;
  #pragma unroll
  for (int sk = 0; sk < SK_; sk++) s += part[(size_t)sk*81920 + i];
  xdbc[i] = s;
}

// ---------------- SSM chunked scan (prefetched) ----------------
// Pq layout per (b,ch,e): [0..15] = P (chunk transfer), [16..31] = q, then
// scan2 overwrites q-slot with h_in for that chunk.
__global__ __launch_bounds__(256) void scan1_k(
    const float* __restrict__ xdbc, const float* __restrict__ xconv,
    const float* __restrict__ A_log, const float* __restrict__ dtw,
    const float* __restrict__ dtb, float* __restrict__ Pq)
{
  int idx = blockIdx.x*256 + threadIdx.x;   // (b*NCH+ch)*INNER + e
  int e  = idx & (INNER_-1);
  int bc = idx >> 11;
  int ch = bc & (NCH_-1);
  int b  = bc >> 5;
  float A[STATE_];
  #pragma unroll
  for (int s=0;s<STATE_;s++) A[s] = -fexp_(A_log[e*STATE_+s]);
  float w[DTR_];
  #pragma unroll
  for (int r=0;r<DTR_;r++) w[r] = dtw[e*DTR_+r];
  float bias = dtb[e];
  float h[STATE_] = {};
  float sdt = 0.f;
  int mbase = b*L_ + ch*CHL_;
  // current-step inputs
  float dtx[DTR_], Bv[STATE_], xcv;
  {
    const float* row = xdbc + (size_t)mbase*40;
    #pragma unroll
    for (int r=0;r<DTR_;r++) dtx[r] = row[r];
    #pragma unroll
    for (int s=0;s<STATE_;s++) Bv[s] = row[8+s];
    xcv = xconv[(size_t)mbase*INNER_ + e];
  }
  for (int l=0;l<CHL_;l++) {
    float ndtx[DTR_], nBv[STATE_], nxcv = 0.f;
    if (l+1 < CHL_) {                 // prefetch next step
      const float* nrow = xdbc + (size_t)(mbase+l+1)*40;
      #pragma unroll
      for (int r=0;r<DTR_;r++) ndtx[r] = nrow[r];
      #pragma unroll
      for (int s=0;s<STATE_;s++) nBv[s] = nrow[8+s];
      nxcv = xconv[(size_t)(mbase+l+1)*INNER_ + e];
    } else {
      #pragma unroll
      for (int r=0;r<DTR_;r++) ndtx[r] = 0.f;
      #pragma unroll
      for (int s=0;s<STATE_;s++) nBv[s] = 0.f;
    }
    float v = bias;
    #pragma unroll
    for (int r=0;r<DTR_;r++) v += dtx[r]*w[r];
    float dt = fsoftplus_(v);
    sdt += dt;
    float dx = dt * xcv;
    #pragma unroll
    for (int s=0;s<STATE_;s++) {
      float dA = fexp_(dt*A[s]);
      h[s] = dA*h[s] + dx*Bv[s];
    }
    #pragma unroll
    for (int r=0;r<DTR_;r++) dtx[r] = ndtx[r];
    #pragma unroll
    for (int s=0;s<STATE_;s++) Bv[s] = nBv[s];
    xcv = nxcv;
  }
  float* o = Pq + (size_t)idx*32;
  #pragma unroll
  for (int s=0;s<STATE_;s++) { o[s] = fexp_(A[s]*sdt); o[16+s] = h[s]; }
}

// combine chunks, parallel over (b,e,s); h_in written into the q slot
__global__ __launch_bounds__(256) void scan2_k(float* __restrict__ Pq)
{
  int idx = blockIdx.x*256 + threadIdx.x;   // b*(INNER*16) + e*16 + s ; 65536
  int s = idx & 15;
  int e = (idx >> 4) & (INNER_-1);
  int b = idx >> 15;
  float h = 0.f;
  for (int ch = 0; ch < NCH_; ch++) {
    size_t base = ((size_t)(b*NCH_+ch)*INNER_ + e)*32;
    float p = Pq[base + s];
    float q = Pq[base + 16 + s];
    Pq[base + 16 + s] = h;
    h = p*h + q;
  }
}

__global__ __launch_bounds__(256) void scan3_k(
    const float* __restrict__ xdbc, const float* __restrict__ xconv,
    const float* __restrict__ A_log, const float* __restrict__ dtw,
    const float* __restrict__ dtb, const float* __restrict__ Dp,
    const float* __restrict__ Pq, u16* __restrict__ ycat)
{
  int idx = blockIdx.x*256 + threadIdx.x;
  int e  = idx & (INNER_-1);
  int bc = idx >> 11;
  int ch = bc & (NCH_-1);
  int b  = bc >> 5;
  float A[STATE_];
  #pragma unroll
  for (int s=0;s<STATE_;s++) A[s] = -fexp_(A_log[e*STATE_+s]);
  float w[DTR_];
  #pragma unroll
  for (int r=0;r<DTR_;r++) w[r] = dtw[e*DTR_+r];
  float bias = dtb[e];
  float Dv = Dp[e];
  float h[STATE_];
  const float* hi = Pq + (size_t)idx*32 + 16;
  #pragma unroll
  for (int s=0;s<STATE_;s++) h[s] = hi[s];
  int mbase = b*L_ + ch*CHL_;
  float dtx[DTR_], Bv[STATE_], Cv[STATE_], xcv;
  {
    const float* row = xdbc + (size_t)mbase*40;
    #pragma unroll
    for (int r=0;r<DTR_;r++) dtx[r] = row[r];
    #pragma unroll
    for (int s=0;s<STATE_;s++) { Bv[s] = row[8+s]; Cv[s] = row[24+s]; }
    xcv = xconv[(size_t)mbase*INNER_ + e];
  }
  for (int l=0;l<CHL_;l++) {
    float ndtx[DTR_], nBv[STATE_], nCv[STATE_], nxcv = 0.f;
    if (l+1 < CHL_) {
      const float* nrow = xdbc + (size_t)(mbase+l+1)*40;
      #pragma unroll
      for (int r=0;r<DTR_;r++) ndtx[r] = nrow[r];
      #pragma unroll
      for (int s=0;s<STATE_;s++) { nBv[s] = nrow[8+s]; nCv[s] = nrow[24+s]; }
      nxcv = xconv[(size_t)(mbase+l+1)*INNER_ + e];
    } else {
      #pragma unroll
      for (int r=0;r<DTR_;r++) ndtx[r] = 0.f;
      #pragma unroll
      for (int s=0;s<STATE_;s++) { nBv[s] = 0.f; nCv[s] = 0.f; }
    }
    float v = bias;
    #pragma unroll
    for (int r=0;r<DTR_;r++) v += dtx[r]*w[r];
    float dt = fsoftplus_(v);
    float dx = dt * xcv;
    float y = 0.f;
    #pragma unroll
    for (int s=0;s<STATE_;s++) {
      float dA = fexp_(dt*A[s]);
      h[s] = dA*h[s] + dx*Bv[s];
      y += h[s]*Cv[s];
    }
    ycat[(size_t)(mbase+l)*4096 + e] = f2bf(y + xcv*Dv);
    #pragma unroll
    for (int r=0;r<DTR_;r++) dtx[r] = ndtx[r];
    #pragma unroll
    for (int s=0;s<STATE_;s++) { Bv[s] = nBv[s]; Cv[s] = nCv[s]; }
    xcv = nxcv;
  }
}

// ---------------- layernorm ----------------
__global__ __launch_bounds__(256) void ln_k(const float* __restrict__ inp,
    const float* __restrict__ gma, const float* __restrict__ bta,
    float* __restrict__ out)
{
  int m = blockIdx.x;
  const float* row = inp + (size_t)m*DM_;
  float s=0.f, s2=0.f;
  float v[4];
  #pragma unroll
  for (int j=0;j<4;j++) {
    v[j] = row[threadIdx.x + j*256];
    s += v[j]; s2 += v[j]*v[j];
  }
  #pragma unroll
  for (int off=32; off>=1; off>>=1) {
    s  += __shfl_down(s, off);
    s2 += __shfl_down(s2, off);
  }
  __shared__ float rs[4], rs2[4], stats[2];
  int wid = threadIdx.x >> 6;
  if ((threadIdx.x & 63) == 0) { rs[wid]=s; rs2[wid]=s2; }
  __syncthreads();
  if (threadIdx.x == 0) {
    float ts  = rs[0]+rs[1]+rs[2]+rs[3];
    float ts2 = rs2[0]+rs2[1]+rs2[2]+rs2[3];
    float mu  = ts/(float)DM_;
    float var = ts2/(float)DM_ - mu*mu;
    stats[0] = mu; stats[1] = rsqrtf(var + 1e-5f);
  }
  __syncthreads();
  float mu = stats[0], rstd = stats[1];
  #pragma unroll
  for (int j=0;j<4;j++) {
    int n = threadIdx.x + j*256;
    out[(size_t)m*DM_ + n] = (v[j]-mu)*rstd*gma[n] + bta[n];
  }
}

extern "C" void kernel_launch(void* const* d_in, const int* in_sizes, int n_in,
                              void* d_out, int out_size, void* d_ws, size_t ws_size,
                              hipStream_t stream)
{
  const float* x       = (const float*)d_in[0];
  const float* in_w    = (const float*)d_in[1];
  const float* conv_w  = (const float*)d_in[2];
  const float* conv_b  = (const float*)d_in[3];
  const float* A_log   = (const float*)d_in[4];
  const float* Dp      = (const float*)d_in[5];
  const float* xproj_w = (const float*)d_in[6];
  const float* dt_w    = (const float*)d_in[7];
  const float* dt_b    = (const float*)d_in[8];
  const float* f_re    = (const float*)d_in[9];
  const float* f_im    = (const float*)d_in[10];
  const float* s_dec   = (const float*)d_in[11];
  const float* fus_w   = (const float*)d_in[12];
  const float* fus_b   = (const float*)d_in[13];
  const float* out_w   = (const float*)d_in[14];
  const float* ln_g    = (const float*)d_in[15];
  const float* ln_b    = (const float*)d_in[16];
  float* out = (float*)d_out;

  // ---- workspace carve (fp32 region then bf16 region), ~137 MB total ----
  float* ws    = (float*)d_ws;
  float* xz    = ws;                       // 8388608  (M x 4096)
  float* xconv = xz    + 8388608;          // 4194304  (M x 2048), reused as outp
  float* xdbc  = xconv + 4194304;          // 81920    (M x 40)
  float* Pq    = xdbc  + 81920;            // 4194304  (B*NCH*INNER x 32), holds h_in too
  u16* ub      = (u16*)(Pq + 4194304);
  u16* xb      = ub;                       // 2097152   x bf16; reused as Winv after in_proj
  u16* inwb    = xb    + 2097152;          // 4194304   in_w bf16; reused as part after in_proj
  u16* fuswb   = inwb  + 4194304;          // 8388608   fus_w bf16
  u16* outwb   = fuswb + 8388608;          // 2097152   out_w bf16
  u16* xt      = outwb + 2097152;          // 4194304   x_inner^T bf16; reused as ycomb
  u16* Wb      = xt    + 4194304;          // 1114112   Wdft (NFP_ x 1024)
  u16* XFb     = Wb    + 1114112;          // 4456448   (MD x NFP_) bf16
  u16* ycat    = XFb   + 4456448;          // 8388608   (M x 4096) bf16
  u16* ycomb   = xt;
  u16* Winv    = xb;                       // 1114112 <= 2097152; xb dead after in_proj
  float* outp  = xconv;
  float* part  = (float*)inwb;             // SK_*M_*40 = 1310720 floats <= 2097152
                                           // (inwb dead after in_proj; NO ycat alias!)

  // 0. convert GEMM operands to bf16 (xb,inwb,fuswb,outwb are contiguous)
  cvt4_k<<<CVT_NT/1024, 256, 0, stream>>>(x, in_w, fus_w, out_w, xb);

  // 1. xz = x @ in_proj_w^T (2048 x 4096 x 1024); epilogue writes xt (bf16 T)
  //    + grid-fused genWdft (2176 extra blocks @ 512 thr)
  mgemm_k<128,128,5,0,1><<<512 + (NFP_*1024)/512, 512, 0, stream>>>(
      xb, inwb, xz, 1024, 4096, nullptr, xt, nullptr, nullptr, 32, 16,
      nullptr, nullptr, nullptr, nullptr, Wb);
  // 2. forward DFT + spectral filter: XFb = filt(xt @ Wdft)   [544 blocks]
  //    + grid-fused conv_silu (2048 blocks) + genWinv (4352 blocks)
  mgemm_k<128,64,3,1,2><<<544 + 2048 + (1024*NFP_)/256, 256, 0, stream>>>(
      xt, Wb, XFb, 1024, NFP_, f_re, nullptr, s_dec, f_im, 17, 32,
      xz, conv_w, conv_b, xconv, Winv);
  // 3. inverse DFT (4096 x 1024 x NFP_); epilogue -> ycat[:,2048:]  [512 blocks]
  //    + grid-fused xproj (SK_*8 = 128 blocks; writes part=inwb, disjoint from ycat)
  mgemm_k<128,64,6,1,3><<<512 + SK_*8, 256, 0, stream>>>(
      XFb, Winv, ycat, NFP_, 0, nullptr, nullptr, nullptr, nullptr, 16, 32,
      xconv, xproj_w, nullptr, part, nullptr);
  // 4. x_dbc reduce
  xpred_k<<<(M_*40)/256, 256, 0, stream>>>(part, xdbc);
  // 5-7. chunked SSM scan -> y_cat[:, :2048] (bf16)
  scan1_k<<<(B_*NCH_*INNER_)/256, 256, 0, stream>>>(xdbc, xconv, A_log, dt_w, dt_b, Pq);
  scan2_k<<<(B_*INNER_*STATE_)/256, 256, 0, stream>>>(Pq);
  scan3_k<<<(B_*NCH_*INNER_)/256, 256, 0, stream>>>(xdbc, xconv, A_log, dt_w, dt_b, Dp, Pq, ycat);
  // 8. fusion GEMM + gate epilogue (2048 x 2048 x 4096) -> ycomb bf16
  mgemm_k<128,64,1,0,0><<<512, 256, 0, stream>>>(
      ycat, fuswb, ycomb, 4096, 2048, fus_b, ycat, xz, nullptr, 32, 16,
      nullptr, nullptr, nullptr, nullptr, nullptr);
  // 9. out proj + residual (2048 x 1024 x 2048) -> fp32
  mgemm_k<64,64,2,1,0><<<512, 128, 0, stream>>>(
      ycomb, outwb, outp, 2048, 1024, nullptr, nullptr, x, nullptr, 16, 32,
      nullptr, nullptr, nullptr, nullptr, nullptr);
  // 10. layernorm -> d_out
  ln_k<<<M_, 256, 0, stream>>>(outp, ln_g, ln_b, out);
}

// Round 5
// 395.528 us; speedup vs baseline: 1.1154x; 1.0204x over previous
//
#include <hip/hip_runtime.h>
#include <math.h>

#define B_ 2
#define L_ 1024
#define DM_ 1024
#define STATE_ 16
#define CONV_ 4
#define DTR_ 8
#define INNER_ 2048
#define M_ (B_*L_)        /* 2048 rows (b,l) */
#define MD_ (B_*INNER_)   /* 4096 rows (b,c) */
#define NFFT_ 513
#define NFP_ 1088         /* 2*513=1026 padded to 17*64 */
#define NCH_ 32
#define CHL_ 32
#define SK_ 16            /* x_proj split-K factor (part fits in dead inwb) */
#define KSL_ (2048/SK_)   /* 128 */

typedef unsigned short u16;
typedef __attribute__((ext_vector_type(8))) short short8;
typedef __attribute__((ext_vector_type(8))) __bf16 bf16x8;
typedef __attribute__((ext_vector_type(4))) float f32x4;

__device__ __forceinline__ float frcp_(float x) { return __builtin_amdgcn_rcpf(x); }
__device__ __forceinline__ float fexp_(float x) { return __expf(x); }
__device__ __forceinline__ float fsigm_(float x) { return frcp_(1.f + __expf(-x)); }
__device__ __forceinline__ float fsilu_(float x) { return x * frcp_(1.f + __expf(-x)); }
__device__ __forceinline__ float fsoftplus_(float v) {
  return (v > 20.f) ? v : __logf(1.f + __expf(v));
}
__device__ __forceinline__ u16 f2bf(float f) {
  union { float f; unsigned u; } v; v.f = f;
  unsigned r = v.u + 0x7fffu + ((v.u >> 16) & 1u);
  return (u16)(r >> 16);
}
__device__ __forceinline__ float bf2f(u16 h) {
  union { unsigned u; float f; } v; v.u = ((unsigned)h) << 16;
  return v.f;
}
__device__ __forceinline__ void gload16(const void* g, void* l) {
  __builtin_amdgcn_global_load_lds(
      (const __attribute__((address_space(1))) unsigned*)g,
      (__attribute__((address_space(3))) unsigned*)l, 16, 0, 0);
}
__device__ __forceinline__ f32x4 mfma_bf16(short8 a, short8 b, f32x4 c) {
  return __builtin_amdgcn_mfma_f32_16x16x32_bf16(
      __builtin_bit_cast(bf16x8, a), __builtin_bit_cast(bf16x8, b), c, 0, 0, 0);
}

// ---------------- fp32 -> bf16 conversion (x + in_w only; rest is aux) ------
#define CVT2_N0 2097152
#define CVT2_NT 6291456
__global__ __launch_bounds__(256) void cvt2_k(
    const float* __restrict__ s0, const float* __restrict__ s1,
    u16* __restrict__ out)
{
  int i = (blockIdx.x*256 + threadIdx.x) * 4;
  const float* src; int off;
  if (i < CVT2_N0) { src = s0; off = 0; }
  else             { src = s1; off = CVT2_N0; }
  float4 v = *(const float4*)(src + (i - off));
  ushort4 o;
  o.x = f2bf(v.x); o.y = f2bf(v.y); o.z = f2bf(v.z); o.w = f2bf(v.w);
  *(ushort4*)(out + i) = o;
}

// ---------------- aux bodies (grid-fused into GEMM launches) ----------------
// 16 contiguous floats per thread -> bf16
__device__ __forceinline__ void cvt16_body(int eb, int nthr, int t,
    const float* __restrict__ src, u16* __restrict__ dst)
{
  int i = (eb*nthr + t)*16;
  #pragma unroll
  for (int q = 0; q < 4; q++) {
    float4 v = *(const float4*)(src + i + q*4);
    ushort4 o;
    o.x = f2bf(v.x); o.y = f2bf(v.y); o.z = f2bf(v.z); o.w = f2bf(v.w);
    *(ushort4*)(dst + i + q*4) = o;
  }
}

// depthwise causal conv(4) + silu, 8 l per thread; idx < M_*INNER_/8
__device__ __forceinline__ void conv_body(int idx, const float* __restrict__ xz,
    const float* __restrict__ cw, const float* __restrict__ cb,
    float* __restrict__ xc)
{
  int c = idx & (INNER_-1);
  int g = idx >> 11;                        // 0..255
  int b = g >> 7;
  int lb = (g & 127) * 8;
  float w0=cw[c*4+0], w1=cw[c*4+1], w2=cw[c*4+2], w3=cw[c*4+3];
  float bias = cb[c];
  float v[11];
  #pragma unroll
  for (int j = 0; j < 11; j++) {
    int l = lb - 3 + j;
    v[j] = (l >= 0) ? xz[((size_t)((b << 10) + l))*4096 + c] : 0.f;
  }
  #pragma unroll
  for (int j = 0; j < 8; j++) {
    float s = bias + w0*v[j] + w1*v[j+1] + w2*v[j+2] + w3*v[j+3];
    xc[((size_t)((b << 10) + lb + j))*INNER_ + c] = fsilu_(s);
  }
}

// DFT matrix (bf16, K-contiguous): W[col*1024 + l], col < NFP_
__device__ __forceinline__ void genWdft_body(int idx, u16* __restrict__ W)
{
  int l = idx & (L_-1);
  int col = idx >> 10;
  float v = 0.f;
  int f = col >> 1;
  if (f < NFFT_) {
    int ph = (l*f) & (L_-1);
    float th = (float)ph * (6.283185307179586f / (float)L_);
    v = (col & 1) ? -__sinf(th) : __cosf(th);
  }
  W[idx] = f2bf(v);
}

// inverse-DFT matrix: W[l*NFP_ + r], l < 1024, r < NFP_
__device__ __forceinline__ void genWinv_body(int idx, u16* __restrict__ W)
{
  int r = idx % NFP_;
  int l = idx / NFP_;
  int f = r >> 1;
  float v = 0.f;
  if (f < NFFT_) {
    bool edge = (f == 0) || (f == 512);
    float sc = (edge ? 1.f : 2.f) / (float)L_;
    int ph = (f*l) & (L_-1);
    float th = (float)ph * (6.283185307179586f / (float)L_);
    if (r & 1) v = edge ? 0.f : -sc*__sinf(th);
    else       v = sc*__cosf(th);
  }
  W[idx] = f2bf(v);
}

// x_proj split-K slice: part[sk][m][40] = xconv[m, sk*KSL_:+KSL_] @ W^T
__device__ __forceinline__ void xproj_body(int eb,
    const float* __restrict__ xconv, const float* __restrict__ W,
    float* __restrict__ part, void* lds)
{
  float (*Bs)[KSL_+4] = (float(*)[KSL_+4])lds;
  const int sk = eb & (SK_-1), mt = eb / SK_;
  const int k0 = sk*KSL_;
  for (int i = threadIdx.x; i < 40*KSL_; i += 256) {
    int n = i / KSL_, k = i & (KSL_-1);
    Bs[n][k] = W[(size_t)n*2048 + k0 + k];
  }
  __syncthreads();
  const int m = mt*256 + threadIdx.x;
  const float* arow = xconv + (size_t)m*2048 + k0;
  float acc[40];
  #pragma unroll
  for (int j=0;j<40;j++) acc[j]=0.f;
  for (int k = 0; k < KSL_; k += 4) {
    float4 a = *(const float4*)(arow + k);
    #pragma unroll
    for (int j = 0; j < 40; j++) {
      float4 b = *(const float4*)&Bs[j][k];
      acc[j] += a.x*b.x + a.y*b.y + a.z*b.z + a.w*b.w;
    }
  }
  float* o = part + ((size_t)sk*M_ + m)*40;
  #pragma unroll
  for (int j = 0; j < 10; j++)
    *(float4*)(o + j*4) = make_float4(acc[j*4], acc[j*4+1], acc[j*4+2], acc[j*4+3]);
}

// ---------------- bf16 MFMA GEMM (templated tile, double-buffered) ----------
// C[m,n] = sum_k A[m,k0+k]*Bt[n,k0+k], k < K (per-split), row stride ldk.
// KS splits along K: grid has KS*gx*gy GEMM blocks; split ks = bid/(gx*gy),
// k0 = ks*K. EPI=7 writes f32 partial to Cout + ks*(gy*TM*ldc).
// Blocks beyond KS*gx*gy run grid-fused aux work (AUX: 1 = genWdft + cvt16;
// 2 = conv, genWinv, cvt16; 3 = xproj), independent of this launch's GEMM
// and writing disjoint memory (audited per launch).
// EPI: 0 plain f32; 3 spectral filter (bf16); 5 in_proj (f32 + bf16 xt^T);
//      6 inv-DFT (bf16 transposed into ycat); 7 f32 split-K partial.
template<int TM, int TN, int EPI, int YCH, int AUX, int KS>
__global__ __launch_bounds__((TM/64)*(TN/32)*64) void mgemm_k(
    const u16* __restrict__ Ab, const u16* __restrict__ Bb,
    void* __restrict__ Cout, int K, int ldc,
    const float* __restrict__ aux0, u16* __restrict__ aux1,
    const float* __restrict__ aux2, const float* __restrict__ aux3,
    int gx, int gy,
    const float* __restrict__ ga, const float* __restrict__ gb,
    const float* __restrict__ gc, float* __restrict__ go,
    u16* __restrict__ gw,
    int ldk, const float* __restrict__ cvs, u16* __restrict__ cvd)
{
  constexpr int WN   = TN/32;
  constexpr int NW   = (TM/64)*WN;
  constexpr int NTHR = NW*64;
  __shared__ __align__(16) u16 As[2][TM*64];
  __shared__ __align__(16) u16 Bs[2][TN*64];
  const int t = threadIdx.x;
  const int nwg = gx * gy;

  if constexpr (AUX != 0) {
    int eb = (int)blockIdx.x - nwg*KS;
    if (eb >= 0) {
      if constexpr (AUX == 1) {              // genWdft (2176) + cvt fus_w (1024)
        if (eb < 2176) genWdft_body(eb*NTHR + t, gw);
        else           cvt16_body(eb - 2176, NTHR, t, cvs, cvd);
      } else if constexpr (AUX == 2) {       // conv (2048) + genWinv (4352) + cvt out_w (512)
        if (eb < 2048)      conv_body(eb*256 + t, ga, gb, gc, go);
        else if (eb < 6400) genWinv_body((eb - 2048)*256 + t, gw);
        else                cvt16_body(eb - 6400, NTHR, t, cvs, cvd);
      } else {                               // 3: xproj (SK_*8 blks)
        xproj_body(eb, ga, gb, go, (void*)&As[0][0]);
      }
      return;
    }
  }

  const int lane = t & 63;
  const int w = t >> 6;
  const int wm = w / WN, wn = w % WN;

  // split-K id + XCD-chunked bijective remap (nwg % 8 == 0 everywhere)
  int bid = blockIdx.x;
  int ks = 0;
  if constexpr (KS > 1) { ks = bid / nwg; bid -= ks*nwg; }
  const int k0 = ks * K;
  const int lid = (bid & 7) * (nwg >> 3) + (bid >> 3);
  int bx, by;
  if (YCH) { by = lid / gx; bx = lid - by*gx; }
  else     { bx = lid / gy; by = lid - bx*gy; }
  const int M0 = by * TM, N0 = bx * TN;

  f32x4 acc[4][2] = {};

  auto stage = [&](int buf, int kk0) {
    #pragma unroll
    for (int q = 0; q < TM*8/NTHR; q++) {
      int u = q*NTHR + t;
      int row = u >> 3, gpr = u & 7;
      int grp = gpr ^ (row & 7);        // XOR swizzle
      gload16(Ab + (size_t)(M0+row)*ldk + k0 + kk0 + grp*8, &As[buf][u*8]);
    }
    #pragma unroll
    for (int q = 0; q < TN*8/NTHR; q++) {
      int u = q*NTHR + t;
      int row = u >> 3, gpr = u & 7;
      int grp = gpr ^ (row & 7);
      gload16(Bb + (size_t)(N0+row)*ldk + k0 + kk0 + grp*8, &Bs[buf][u*8]);
    }
  };

  stage(0, 0);
  const int nk = K >> 6;
  for (int kst = 0; kst < nk; kst++) {
    const int buf = kst & 1;
    __syncthreads();                    // drain stage(buf); protect buf^1 overwrite
    if (kst + 1 < nk) stage(buf ^ 1, (kst + 1) << 6);
    const u16* Asb = As[buf];
    const u16* Bsb = Bs[buf];
    #pragma unroll
    for (int kk = 0; kk < 2; kk++) {
      const int quad = lane >> 4;
      const int grp = kk*4 + quad;
      short8 af[4], bfr[2];
      #pragma unroll
      for (int i = 0; i < 4; i++) {
        int row = wm*64 + i*16 + (lane & 15);
        af[i] = *(const short8*)&Asb[(row*8 + (grp ^ (row & 7)))*8];
      }
      #pragma unroll
      for (int j = 0; j < 2; j++) {
        int row = wn*32 + j*16 + (lane & 15);
        bfr[j] = *(const short8*)&Bsb[(row*8 + (grp ^ (row & 7)))*8];
      }
      #pragma unroll
      for (int i = 0; i < 4; i++)
        #pragma unroll
        for (int j = 0; j < 2; j++)
          acc[i][j] = mfma_bf16(af[i], bfr[j], acc[i][j]);
    }
  }

  // C/D layout: col = lane&15, row = (lane>>4)*4 + r
  #pragma unroll
  for (int i = 0; i < 4; i++) {
    int mbase = M0 + wm*64 + i*16 + (lane >> 4)*4;
    #pragma unroll
    for (int j = 0; j < 2; j++) {
      int n = N0 + wn*32 + j*16 + (lane & 15);
      #pragma unroll
      for (int r = 0; r < 4; r++) {
        int m = mbase + r;
        float v = acc[i][j][r];
        if (EPI == 0) {
          ((float*)Cout)[(size_t)m*ldc + n] = v;
        } else if (EPI == 3) {          // spectral filter, complex pair via shfl
          float pv = __shfl_xor(v, 1, 64);
          int f = n >> 1;
          float outv = 0.f;
          if (f < NFFT_) {
            int c = m & (INNER_-1);
            float d  = fexp_(-aux2[c] * (float)f * (1.f/512.f));
            float wr = aux0[c*NFFT_+f]*d, wi = aux3[c*NFFT_+f]*d;
            float a = (n & 1) ? pv : v;
            float b = (n & 1) ? v : pv;
            outv = (n & 1) ? (a*wi + b*wr) : (a*wr - b*wi);
          }
          ((u16*)Cout)[(size_t)m*ldc + n] = f2bf(outv);
        } else if (EPI == 5) {          // in_proj: xz f32 + transposed bf16 xt
          ((float*)Cout)[(size_t)m*ldc + n] = v;
          if (n < 2048) {
            int b2 = m >> 10, l2 = m & 1023;
            aux1[((size_t)(b2*2048 + n) << 10) + l2] = f2bf(v);
          }
        } else if (EPI == 6) {          // inv-DFT transposed into ycat
          int b2 = m >> 11, c2 = m & (INNER_-1);
          ((u16*)Cout)[((size_t)((b2 << 10) + n) << 12) + 2048 + c2] = f2bf(v);
        } else {                        // 7: f32 split-K partial
          float* P = (float*)Cout + (size_t)ks * ((size_t)gy*TM*ldc);
          P[(size_t)m*ldc + n] = v;
        }
      }
    }
  }
}

// ---------------- fusion combine: gate epilogue over summed partials --------
__global__ __launch_bounds__(256) void combine_gate_k(
    const float* __restrict__ P, const float* __restrict__ fus_b,
    const u16* __restrict__ ycat, const float* __restrict__ xz,
    u16* __restrict__ ycomb)
{
  int i4 = (blockIdx.x*256 + threadIdx.x)*4;   // m*2048 + n
  int m = i4 >> 11, n = i4 & 2047;
  float4 p0 = *(const float4*)(P + i4);
  float4 p1 = *(const float4*)(P + 4194304 + i4);
  ushort4 ysv = *(const ushort4*)(ycat + (size_t)m*4096 + n);
  ushort4 ypv = *(const ushort4*)(ycat + (size_t)m*4096 + 2048 + n);
  float4 zv = *(const float4*)(xz + (size_t)m*4096 + 2048 + n);
  float4 fb = *(const float4*)(fus_b + n);
  float pp[4] = {p0.x+p1.x, p0.y+p1.y, p0.z+p1.z, p0.w+p1.w};
  float zz[4] = {zv.x, zv.y, zv.z, zv.w};
  float bb[4] = {fb.x, fb.y, fb.z, fb.w};
  u16 ys[4] = {ysv.x, ysv.y, ysv.z, ysv.w};
  u16 yp[4] = {ypv.x, ypv.y, ypv.z, ypv.w};
  ushort4 o;
  u16* op = (u16*)&o;
  #pragma unroll
  for (int j = 0; j < 4; j++) {
    float g = fsigm_(pp[j] + bb[j]);
    op[j] = f2bf((g*bf2f(ys[j]) + (1.f-g)*bf2f(yp[j]))*fsilu_(zz[j]));
  }
  *(ushort4*)(ycomb + i4) = o;
}

__global__ __launch_bounds__(256) void xpred_k(const float* __restrict__ part,
                                               float* __restrict__ xdbc)
{
  int i = blockIdx.x*256 + threadIdx.x;   // 81920 total
  float s = 0.f;
  #pragma unroll
  for (int sk = 0; sk < SK_; sk++) s += part[(size_t)sk*81920 + i];
  xdbc[i] = s;
}

// ---------------- SSM chunked scan (prefetched) ----------------
__global__ __launch_bounds__(256) void scan1_k(
    const float* __restrict__ xdbc, const float* __restrict__ xconv,
    const float* __restrict__ A_log, const float* __restrict__ dtw,
    const float* __restrict__ dtb, float* __restrict__ Pq)
{
  int idx = blockIdx.x*256 + threadIdx.x;   // (b*NCH+ch)*INNER + e
  int e  = idx & (INNER_-1);
  int bc = idx >> 11;
  int ch = bc & (NCH_-1);
  int b  = bc >> 5;
  float A[STATE_];
  #pragma unroll
  for (int s=0;s<STATE_;s++) A[s] = -fexp_(A_log[e*STATE_+s]);
  float w[DTR_];
  #pragma unroll
  for (int r=0;r<DTR_;r++) w[r] = dtw[e*DTR_+r];
  float bias = dtb[e];
  float h[STATE_] = {};
  float sdt = 0.f;
  int mbase = b*L_ + ch*CHL_;
  float dtx[DTR_], Bv[STATE_], xcv;
  {
    const float* row = xdbc + (size_t)mbase*40;
    #pragma unroll
    for (int r=0;r<DTR_;r++) dtx[r] = row[r];
    #pragma unroll
    for (int s=0;s<STATE_;s++) Bv[s] = row[8+s];
    xcv = xconv[(size_t)mbase*INNER_ + e];
  }
  for (int l=0;l<CHL_;l++) {
    float ndtx[DTR_], nBv[STATE_], nxcv = 0.f;
    if (l+1 < CHL_) {
      const float* nrow = xdbc + (size_t)(mbase+l+1)*40;
      #pragma unroll
      for (int r=0;r<DTR_;r++) ndtx[r] = nrow[r];
      #pragma unroll
      for (int s=0;s<STATE_;s++) nBv[s] = nrow[8+s];
      nxcv = xconv[(size_t)(mbase+l+1)*INNER_ + e];
    } else {
      #pragma unroll
      for (int r=0;r<DTR_;r++) ndtx[r] = 0.f;
      #pragma unroll
      for (int s=0;s<STATE_;s++) nBv[s] = 0.f;
    }
    float v = bias;
    #pragma unroll
    for (int r=0;r<DTR_;r++) v += dtx[r]*w[r];
    float dt = fsoftplus_(v);
    sdt += dt;
    float dx = dt * xcv;
    #pragma unroll
    for (int s=0;s<STATE_;s++) {
      float dA = fexp_(dt*A[s]);
      h[s] = dA*h[s] + dx*Bv[s];
    }
    #pragma unroll
    for (int r=0;r<DTR_;r++) dtx[r] = ndtx[r];
    #pragma unroll
    for (int s=0;s<STATE_;s++) Bv[s] = nBv[s];
    xcv = nxcv;
  }
  float* o = Pq + (size_t)idx*32;
  #pragma unroll
  for (int s=0;s<STATE_;s++) { o[s] = fexp_(A[s]*sdt); o[16+s] = h[s]; }
}

__global__ __launch_bounds__(256) void scan2_k(float* __restrict__ Pq)
{
  int idx = blockIdx.x*256 + threadIdx.x;   // 65536
  int s = idx & 15;
  int e = (idx >> 4) & (INNER_-1);
  int b = idx >> 15;
  float h = 0.f;
  for (int ch = 0; ch < NCH_; ch++) {
    size_t base = ((size_t)(b*NCH_+ch)*INNER_ + e)*32;
    float p = Pq[base + s];
    float q = Pq[base + 16 + s];
    Pq[base + 16 + s] = h;
    h = p*h + q;
  }
}

__global__ __launch_bounds__(256) void scan3_k(
    const float* __restrict__ xdbc, const float* __restrict__ xconv,
    const float* __restrict__ A_log, const float* __restrict__ dtw,
    const float* __restrict__ dtb, const float* __restrict__ Dp,
    const float* __restrict__ Pq, u16* __restrict__ ycat)
{
  int idx = blockIdx.x*256 + threadIdx.x;
  int e  = idx & (INNER_-1);
  int bc = idx >> 11;
  int ch = bc & (NCH_-1);
  int b  = bc >> 5;
  float A[STATE_];
  #pragma unroll
  for (int s=0;s<STATE_;s++) A[s] = -fexp_(A_log[e*STATE_+s]);
  float w[DTR_];
  #pragma unroll
  for (int r=0;r<DTR_;r++) w[r] = dtw[e*DTR_+r];
  float bias = dtb[e];
  float Dv = Dp[e];
  float h[STATE_];
  const float* hi = Pq + (size_t)idx*32 + 16;
  #pragma unroll
  for (int s=0;s<STATE_;s++) h[s] = hi[s];
  int mbase = b*L_ + ch*CHL_;
  float dtx[DTR_], Bv[STATE_], Cv[STATE_], xcv;
  {
    const float* row = xdbc + (size_t)mbase*40;
    #pragma unroll
    for (int r=0;r<DTR_;r++) dtx[r] = row[r];
    #pragma unroll
    for (int s=0;s<STATE_;s++) { Bv[s] = row[8+s]; Cv[s] = row[24+s]; }
    xcv = xconv[(size_t)mbase*INNER_ + e];
  }
  for (int l=0;l<CHL_;l++) {
    float ndtx[DTR_], nBv[STATE_], nCv[STATE_], nxcv = 0.f;
    if (l+1 < CHL_) {
      const float* nrow = xdbc + (size_t)(mbase+l+1)*40;
      #pragma unroll
      for (int r=0;r<DTR_;r++) ndtx[r] = nrow[r];
      #pragma unroll
      for (int s=0;s<STATE_;s++) { nBv[s] = nrow[8+s]; nCv[s] = nrow[24+s]; }
      nxcv = xconv[(size_t)(mbase+l+1)*INNER_ + e];
    } else {
      #pragma unroll
      for (int r=0;r<DTR_;r++) ndtx[r] = 0.f;
      #pragma unroll
      for (int s=0;s<STATE_;s++) { nBv[s] = 0.f; nCv[s] = 0.f; }
    }
    float v = bias;
    #pragma unroll
    for (int r=0;r<DTR_;r++) v += dtx[r]*w[r];
    float dt = fsoftplus_(v);
    float dx = dt * xcv;
    float y = 0.f;
    #pragma unroll
    for (int s=0;s<STATE_;s++) {
      float dA = fexp_(dt*A[s]);
      h[s] = dA*h[s] + dx*Bv[s];
      y += h[s]*Cv[s];
    }
    ycat[(size_t)(mbase+l)*4096 + e] = f2bf(y + xcv*Dv);
    #pragma unroll
    for (int r=0;r<DTR_;r++) dtx[r] = ndtx[r];
    #pragma unroll
    for (int s=0;s<STATE_;s++) { Bv[s] = nBv[s]; Cv[s] = nCv[s]; }
    xcv = nxcv;
  }
}

// ---------------- layernorm over summed out_proj partials + residual --------
__global__ __launch_bounds__(256) void ln2_k(const float* __restrict__ Q,
    const float* __restrict__ xres,
    const float* __restrict__ gma, const float* __restrict__ bta,
    float* __restrict__ out)
{
  int m = blockIdx.x;
  float s=0.f, s2=0.f;
  float v[4];
  #pragma unroll
  for (int j=0;j<4;j++) {
    int n = threadIdx.x + j*256;
    size_t idx = (size_t)m*DM_ + n;
    v[j] = Q[idx] + Q[2097152 + idx] + xres[idx];
    s += v[j]; s2 += v[j]*v[j];
  }
  #pragma unroll
  for (int off=32; off>=1; off>>=1) {
    s  += __shfl_down(s, off);
    s2 += __shfl_down(s2, off);
  }
  __shared__ float rs[4], rs2[4], stats[2];
  int wid = threadIdx.x >> 6;
  if ((threadIdx.x & 63) == 0) { rs[wid]=s; rs2[wid]=s2; }
  __syncthreads();
  if (threadIdx.x == 0) {
    float ts  = rs[0]+rs[1]+rs[2]+rs[3];
    float ts2 = rs2[0]+rs2[1]+rs2[2]+rs2[3];
    float mu  = ts/(float)DM_;
    float var = ts2/(float)DM_ - mu*mu;
    stats[0] = mu; stats[1] = rsqrtf(var + 1e-5f);
  }
  __syncthreads();
  float mu = stats[0], rstd = stats[1];
  #pragma unroll
  for (int j=0;j<4;j++) {
    int n = threadIdx.x + j*256;
    out[(size_t)m*DM_ + n] = (v[j]-mu)*rstd*gma[n] + bta[n];
  }
}

extern "C" void kernel_launch(void* const* d_in, const int* in_sizes, int n_in,
                              void* d_out, int out_size, void* d_ws, size_t ws_size,
                              hipStream_t stream)
{
  const float* x       = (const float*)d_in[0];
  const float* in_w    = (const float*)d_in[1];
  const float* conv_w  = (const float*)d_in[2];
  const float* conv_b  = (const float*)d_in[3];
  const float* A_log   = (const float*)d_in[4];
  const float* Dp      = (const float*)d_in[5];
  const float* xproj_w = (const float*)d_in[6];
  const float* dt_w    = (const float*)d_in[7];
  const float* dt_b    = (const float*)d_in[8];
  const float* f_re    = (const float*)d_in[9];
  const float* f_im    = (const float*)d_in[10];
  const float* s_dec   = (const float*)d_in[11];
  const float* fus_w   = (const float*)d_in[12];
  const float* fus_b   = (const float*)d_in[13];
  const float* out_w   = (const float*)d_in[14];
  const float* ln_g    = (const float*)d_in[15];
  const float* ln_b    = (const float*)d_in[16];
  float* out = (float*)d_out;

  // ---- workspace carve (fp32 region then bf16 region), ~137 MB total ----
  float* ws    = (float*)d_ws;
  float* xz    = ws;                       // 8388608  (M x 4096)
  float* xconv = xz    + 8388608;          // 4194304  (M x 2048)
  float* xdbc  = xconv + 4194304;          // 81920    (M x 40)
  float* Pq    = xdbc  + 81920;            // 4194304  (B*NCH*INNER x 32)
  u16* ub      = (u16*)(Pq + 4194304);
  u16* xb      = ub;                       // 2097152   x bf16; reused as Winv
  u16* inwb    = xb    + 2097152;          // 4194304   in_w bf16; reused as part
  u16* fuswb   = inwb  + 4194304;          // 8388608   fus_w bf16 (converted as L1 aux)
  u16* outwb   = fuswb + 8388608;          // 2097152   out_w bf16 (converted as L2 aux)
  u16* xt      = outwb + 2097152;          // 4194304   x_inner^T bf16; reused as ycomb
  u16* Wb      = xt    + 4194304;          // 1114112   Wdft (NFP_ x 1024)
  u16* XFb     = Wb    + 1114112;          // 4456448   (MD x NFP_) bf16
  u16* ycat    = XFb   + 4456448;          // 8388608   (M x 4096) bf16
  u16* ycomb   = xt;
  u16* Winv    = xb;                       // xb dead after in_proj
  float* part  = (float*)inwb;             // SK_*M_*40 = 1310720 f; inwb dead after L1
  // fusion split-K partials: 2 x 2048x2048 f32 = 8388608 f over the dead
  // [xconv, xdbc, Pq] span (8470528 f available; all dead after scan3)
  float* fpart = xconv;
  // out_proj split-K partials: 2 x 2048x1024 f32 = 4194304 f over dead Pq
  float* opart = Pq;

  // 0. convert x + in_w to bf16 (fus_w/out_w converted as aux in L1/L2)
  cvt2_k<<<CVT2_NT/1024, 256, 0, stream>>>(x, in_w, xb);

  // 1. xz = x @ in_proj_w^T (2048 x 4096 x 1024); epilogue writes xt (bf16 T)
  //    + aux genWdft (2176 blks) + aux cvt fus_w (1024 blks)
  mgemm_k<128,128,5,0,1,1><<<512 + 2176 + 1024, 512, 0, stream>>>(
      xb, inwb, xz, 1024, 4096, nullptr, xt, nullptr, nullptr, 32, 16,
      nullptr, nullptr, nullptr, nullptr, Wb, 1024, fus_w, fuswb);
  // 2. forward DFT + spectral filter: XFb = filt(xt @ Wdft)   [544 GEMM blocks]
  //    + aux conv (2048) + genWinv (4352) + cvt out_w (512)
  mgemm_k<128,64,3,1,2,1><<<544 + 2048 + 4352 + 512, 256, 0, stream>>>(
      xt, Wb, XFb, 1024, NFP_, f_re, nullptr, s_dec, f_im, 17, 32,
      xz, conv_w, conv_b, xconv, Winv, 1024, out_w, outwb);
  // 3. inverse DFT (4096 x 1024 x NFP_); epilogue -> ycat[:,2048:]  [512 blocks]
  //    + aux xproj (128 blocks; part=inwb, disjoint)
  mgemm_k<128,64,6,1,3,1><<<512 + SK_*8, 256, 0, stream>>>(
      XFb, Winv, ycat, NFP_, 0, nullptr, nullptr, nullptr, nullptr, 16, 32,
      xconv, xproj_w, nullptr, part, nullptr, NFP_, nullptr, nullptr);
  // 4. x_dbc reduce
  xpred_k<<<(M_*40)/256, 256, 0, stream>>>(part, xdbc);
  // 5-7. chunked SSM scan -> y_cat[:, :2048] (bf16)
  scan1_k<<<(B_*NCH_*INNER_)/256, 256, 0, stream>>>(xdbc, xconv, A_log, dt_w, dt_b, Pq);
  scan2_k<<<(B_*INNER_*STATE_)/256, 256, 0, stream>>>(Pq);
  scan3_k<<<(B_*NCH_*INNER_)/256, 256, 0, stream>>>(xdbc, xconv, A_log, dt_w, dt_b, Dp, Pq, ycat);
  // 8a. fusion GEMM split-K x2 (2048 x 2048 x 4096), 128x128 tile, 8 waves:
  //     512 blocks = 2/CU x 8 waves = 16 waves/CU; f32 partials -> fpart
  mgemm_k<128,128,7,0,0,2><<<2*256, 512, 0, stream>>>(
      ycat, fuswb, fpart, 2048, 2048, nullptr, nullptr, nullptr, nullptr, 16, 16,
      nullptr, nullptr, nullptr, nullptr, nullptr, 4096, nullptr, nullptr);
  // 8b. combine partials + gate epilogue -> ycomb bf16
  combine_gate_k<<<(2048*2048/4)/256, 256, 0, stream>>>(
      fpart, fus_b, ycat, xz, ycomb);
  // 9. out proj split-K x2 (2048 x 1024 x 2048) -> f32 partials in opart
  mgemm_k<64,64,7,1,0,2><<<2*512, 128, 0, stream>>>(
      ycomb, outwb, opart, 1024, 1024, nullptr, nullptr, nullptr, nullptr, 16, 32,
      nullptr, nullptr, nullptr, nullptr, nullptr, 2048, nullptr, nullptr);
  // 10. layernorm over (partial0 + partial1 + residual) -> d_out
  ln2_k<<<M_, 256, 0, stream>>>(opart, x, ln_g, ln_b, out);
}

// Round 6
// 369.885 us; speedup vs baseline: 1.1928x; 1.0693x over previous
//
#include <hip/hip_runtime.h>
#include <math.h>

#define B_ 2
#define L_ 1024
#define DM_ 1024
#define STATE_ 16
#define CONV_ 4
#define DTR_ 8
#define INNER_ 2048
#define M_ (B_*L_)        /* 2048 rows (b,l) */
#define MD_ (B_*INNER_)   /* 4096 rows (b,c) */
#define NFFT_ 513
#define NFP_ 1088         /* 2*513=1026 padded to 17*64 */
#define NCH_ 32
#define CHL_ 32
#define SK_ 16            /* x_proj split-K factor */
#define KSL_ (2048/SK_)   /* 128 */

typedef unsigned short u16;
typedef __attribute__((ext_vector_type(8))) short short8;
typedef __attribute__((ext_vector_type(8))) __bf16 bf16x8;
typedef __attribute__((ext_vector_type(4))) float f32x4;

__device__ __forceinline__ float frcp_(float x) { return __builtin_amdgcn_rcpf(x); }
__device__ __forceinline__ float fexp_(float x) { return __expf(x); }
__device__ __forceinline__ float fsigm_(float x) { return frcp_(1.f + __expf(-x)); }
__device__ __forceinline__ float fsilu_(float x) { return x * frcp_(1.f + __expf(-x)); }
__device__ __forceinline__ float fsoftplus_(float v) {
  return (v > 20.f) ? v : __logf(1.f + __expf(v));
}
__device__ __forceinline__ u16 f2bf(float f) {
  union { float f; unsigned u; } v; v.f = f;
  unsigned r = v.u + 0x7fffu + ((v.u >> 16) & 1u);
  return (u16)(r >> 16);
}
__device__ __forceinline__ float bf2f(u16 h) {
  union { unsigned u; float f; } v; v.u = ((unsigned)h) << 16;
  return v.f;
}
__device__ __forceinline__ void gload16(const void* g, void* l) {
  __builtin_amdgcn_global_load_lds(
      (const __attribute__((address_space(1))) unsigned*)g,
      (__attribute__((address_space(3))) unsigned*)l, 16, 0, 0);
}
__device__ __forceinline__ f32x4 mfma_bf16(short8 a, short8 b, f32x4 c) {
  return __builtin_amdgcn_mfma_f32_16x16x32_bf16(
      __builtin_bit_cast(bf16x8, a), __builtin_bit_cast(bf16x8, b), c, 0, 0, 0);
}

// ---------------- fp32 -> bf16 conversion (x + in_w only) -------------------
#define CVT2_N0 2097152
#define CVT2_NT 6291456
__global__ __launch_bounds__(256) void cvt2_k(
    const float* __restrict__ s0, const float* __restrict__ s1,
    u16* __restrict__ out)
{
  int i = (blockIdx.x*256 + threadIdx.x) * 4;
  const float* src; int off;
  if (i < CVT2_N0) { src = s0; off = 0; }
  else             { src = s1; off = CVT2_N0; }
  float4 v = *(const float4*)(src + (i - off));
  ushort4 o;
  o.x = f2bf(v.x); o.y = f2bf(v.y); o.z = f2bf(v.z); o.w = f2bf(v.w);
  *(ushort4*)(out + i) = o;
}

// ---------------- aux bodies ------------------------------------------------
// 16 contiguous floats per thread -> bf16
__device__ __forceinline__ void cvt16_body(int eb, int nthr, int t,
    const float* __restrict__ src, u16* __restrict__ dst)
{
  int i = (eb*nthr + t)*16;
  #pragma unroll
  for (int q = 0; q < 4; q++) {
    float4 v = *(const float4*)(src + i + q*4);
    ushort4 o;
    o.x = f2bf(v.x); o.y = f2bf(v.y); o.z = f2bf(v.z); o.w = f2bf(v.w);
    *(ushort4*)(dst + i + q*4) = o;
  }
}

// depthwise causal conv(4) + silu, 8 l per thread; ALSO emits x_inner^T bf16
// (pre-conv values) coalesced into xt[b*2048+c][l] for the DFT GEMM.
__device__ __forceinline__ void conv_xt_body(int idx, const float* __restrict__ xz,
    const float* __restrict__ cw, const float* __restrict__ cb,
    float* __restrict__ xc, u16* __restrict__ xt)
{
  int c = idx & (INNER_-1);
  int g = idx >> 11;                        // 0..255
  int b = g >> 7;
  int lb = (g & 127) * 8;
  float w0=cw[c*4+0], w1=cw[c*4+1], w2=cw[c*4+2], w3=cw[c*4+3];
  float bias = cb[c];
  float v[11];
  #pragma unroll
  for (int j = 0; j < 11; j++) {
    int l = lb - 3 + j;
    v[j] = (l >= 0) ? xz[((size_t)((b << 10) + l))*4096 + c] : 0.f;
  }
  union { u16 a[8]; short8 v8; } tu;
  #pragma unroll
  for (int j = 0; j < 8; j++) tu.a[j] = f2bf(v[j+3]);
  *(short8*)&xt[(((size_t)(b*INNER_ + c)) << 10) + lb] = tu.v8;
  #pragma unroll
  for (int j = 0; j < 8; j++) {
    float s = bias + w0*v[j] + w1*v[j+1] + w2*v[j+2] + w3*v[j+3];
    xc[((size_t)((b << 10) + lb + j))*INNER_ + c] = fsilu_(s);
  }
}

// DFT matrix (bf16, K-contiguous): W[col*1024 + l], col < NFP_
__device__ __forceinline__ void genWdft_body(int idx, u16* __restrict__ W)
{
  int l = idx & (L_-1);
  int col = idx >> 10;
  float v = 0.f;
  int f = col >> 1;
  if (f < NFFT_) {
    int ph = (l*f) & (L_-1);
    float th = (float)ph * (6.283185307179586f / (float)L_);
    v = (col & 1) ? -__sinf(th) : __cosf(th);
  }
  W[idx] = f2bf(v);
}

// inverse-DFT matrix: W[l*NFP_ + r], l < 1024, r < NFP_
__device__ __forceinline__ void genWinv_body(int idx, u16* __restrict__ W)
{
  int r = idx % NFP_;
  int l = idx / NFP_;
  int f = r >> 1;
  float v = 0.f;
  if (f < NFFT_) {
    bool edge = (f == 0) || (f == 512);
    float sc = (edge ? 1.f : 2.f) / (float)L_;
    int ph = (f*l) & (L_-1);
    float th = (float)ph * (6.283185307179586f / (float)L_);
    if (r & 1) v = edge ? 0.f : -sc*__sinf(th);
    else       v = sc*__cosf(th);
  }
  W[idx] = f2bf(v);
}

// x_proj split-K slice: part[sk][m][40] = xconv[m, sk*KSL_:+KSL_] @ W^T
__device__ __forceinline__ void xproj_body(int eb,
    const float* __restrict__ xconv, const float* __restrict__ W,
    float* __restrict__ part, void* lds)
{
  float (*Bs)[KSL_+4] = (float(*)[KSL_+4])lds;
  const int sk = eb & (SK_-1), mt = eb / SK_;
  const int k0 = sk*KSL_;
  for (int i = threadIdx.x; i < 40*KSL_; i += 256) {
    int n = i / KSL_, k = i & (KSL_-1);
    Bs[n][k] = W[(size_t)n*2048 + k0 + k];
  }
  __syncthreads();
  const int m = mt*256 + threadIdx.x;
  const float* arow = xconv + (size_t)m*2048 + k0;
  float acc[40];
  #pragma unroll
  for (int j=0;j<40;j++) acc[j]=0.f;
  for (int k = 0; k < KSL_; k += 4) {
    float4 a = *(const float4*)(arow + k);
    #pragma unroll
    for (int j = 0; j < 40; j++) {
      float4 b = *(const float4*)&Bs[j][k];
      acc[j] += a.x*b.x + a.y*b.y + a.z*b.z + a.w*b.w;
    }
  }
  float* o = part + ((size_t)sk*M_ + m)*40;
  #pragma unroll
  for (int j = 0; j < 10; j++)
    *(float4*)(o + j*4) = make_float4(acc[j*4], acc[j*4+1], acc[j*4+2], acc[j*4+3]);
}

// x_dbc reduce over SK_ partials; i < M_*40
__device__ __forceinline__ void xpred_body(int i, const float* __restrict__ part,
                                           float* __restrict__ xdbc)
{
  float s = 0.f;
  #pragma unroll
  for (int sk = 0; sk < SK_; sk++) s += part[(size_t)sk*81920 + i];
  xdbc[i] = s;
}

// ---------------- standalone aux launch: conv+xt, genWinv, cvt out_w --------
__global__ __launch_bounds__(256) void aux2_k(
    const float* __restrict__ xz, const float* __restrict__ cw,
    const float* __restrict__ cb, float* __restrict__ xc,
    u16* __restrict__ xt, u16* __restrict__ Winv,
    const float* __restrict__ ows, u16* __restrict__ owd)
{
  int eb = blockIdx.x;
  if (eb < 2048)      conv_xt_body(eb*256 + threadIdx.x, xz, cw, cb, xc, xt);
  else if (eb < 6400) genWinv_body((eb - 2048)*256 + threadIdx.x, Winv);
  else                cvt16_body(eb - 6400, 256, threadIdx.x, ows, owd);
}

// ---------------- bf16 MFMA GEMM (templated tile, double-buffered) ----------
// C[m,n] = sum_k A[m,k0+k]*Bt[n,k0+k], k < K (per-split), row stride ldk.
// KS splits along K; split ks = bid/(gx*gy), k0 = ks*K.
// AUX blocks beyond KS*gx*gy: 1 = genWdft + cvt16 fus_w; 3 = xproj;
// 4 = xpred. All independent of this launch's GEMM + disjoint memory.
// EPI: 0 plain f32; 3 spectral filter (bf16); 6 inv-DFT via LDS-transpose
//      (coalesced 16B stores into ycat[:,2048:]); 7 f32 split-K partial;
//      8 bf16 split-K partial.
template<int TM, int TN, int EPI, int YCH, int AUX, int KS>
__global__ __launch_bounds__((TM/64)*(TN/32)*64) void mgemm_k(
    const u16* __restrict__ Ab, const u16* __restrict__ Bb,
    void* __restrict__ Cout, int K, int ldc,
    const float* __restrict__ aux0, u16* __restrict__ aux1,
    const float* __restrict__ aux2, const float* __restrict__ aux3,
    int gx, int gy,
    const float* __restrict__ ga, const float* __restrict__ gb,
    float* __restrict__ go, u16* __restrict__ gw,
    int ldk, const float* __restrict__ cvs, u16* __restrict__ cvd)
{
  constexpr int WN   = TN/32;
  constexpr int NW   = (TM/64)*WN;
  constexpr int NTHR = NW*64;
  __shared__ __align__(16) u16 As[2][TM*64];
  __shared__ __align__(16) u16 Bs[2][TN*64];
  const int t = threadIdx.x;
  const int nwg = gx * gy;

  if constexpr (AUX != 0) {
    int eb = (int)blockIdx.x - nwg*KS;
    if (eb >= 0) {
      if constexpr (AUX == 1) {              // genWdft (2176) + cvt fus_w (1024)
        if (eb < 2176) genWdft_body(eb*NTHR + t, gw);
        else           cvt16_body(eb - 2176, NTHR, t, cvs, cvd);
      } else if constexpr (AUX == 3) {       // xproj (SK_*8 = 128 blks)
        xproj_body(eb, ga, gb, go, (void*)&As[0][0]);
      } else {                               // 4: xpred (320 blks)
        xpred_body(eb*256 + t, ga, go);
      }
      return;
    }
  }

  const int lane = t & 63;
  const int w = t >> 6;
  const int wm = w / WN, wn = w % WN;

  // split-K id + XCD-chunked bijective remap (nwg % 8 == 0 everywhere)
  int bid = blockIdx.x;
  int ks = 0;
  if constexpr (KS > 1) { ks = bid / nwg; bid -= ks*nwg; }
  const int k0 = ks * K;
  const int lid = (bid & 7) * (nwg >> 3) + (bid >> 3);
  int bx, by;
  if (YCH) { by = lid / gx; bx = lid - by*gx; }
  else     { bx = lid / gy; by = lid - bx*gy; }
  const int M0 = by * TM, N0 = bx * TN;

  f32x4 acc[4][2] = {};

  auto stage = [&](int buf, int kk0) {
    #pragma unroll
    for (int q = 0; q < TM*8/NTHR; q++) {
      int u = q*NTHR + t;
      int row = u >> 3, gpr = u & 7;
      int grp = gpr ^ (row & 7);        // XOR swizzle
      gload16(Ab + (size_t)(M0+row)*ldk + k0 + kk0 + grp*8, &As[buf][u*8]);
    }
    #pragma unroll
    for (int q = 0; q < TN*8/NTHR; q++) {
      int u = q*NTHR + t;
      int row = u >> 3, gpr = u & 7;
      int grp = gpr ^ (row & 7);
      gload16(Bb + (size_t)(N0+row)*ldk + k0 + kk0 + grp*8, &Bs[buf][u*8]);
    }
  };

  stage(0, 0);
  const int nk = K >> 6;
  for (int kst = 0; kst < nk; kst++) {
    const int buf = kst & 1;
    __syncthreads();                    // drain stage(buf); protect buf^1 overwrite
    if (kst + 1 < nk) stage(buf ^ 1, (kst + 1) << 6);
    const u16* Asb = As[buf];
    const u16* Bsb = Bs[buf];
    #pragma unroll
    for (int kk = 0; kk < 2; kk++) {
      const int quad = lane >> 4;
      const int grp = kk*4 + quad;
      short8 af[4], bfr[2];
      #pragma unroll
      for (int i = 0; i < 4; i++) {
        int row = wm*64 + i*16 + (lane & 15);
        af[i] = *(const short8*)&Asb[(row*8 + (grp ^ (row & 7)))*8];
      }
      #pragma unroll
      for (int j = 0; j < 2; j++) {
        int row = wn*32 + j*16 + (lane & 15);
        bfr[j] = *(const short8*)&Bsb[(row*8 + (grp ^ (row & 7)))*8];
      }
      #pragma unroll
      for (int i = 0; i < 4; i++)
        #pragma unroll
        for (int j = 0; j < 2; j++)
          acc[i][j] = mfma_bf16(af[i], bfr[j], acc[i][j]);
    }
  }

  if constexpr (EPI == 6) {
    // LDS-transpose epilogue: tile [c_loc 128][l_loc 64] -> coalesced 16B
    // stores into ycat[(b,l) row][2048 + c]. Pad 66 breaks bank aliasing.
    u16* T = (u16*)&As[0][0];           // 128*66*2 = 16.9KB <= 32KB As
    __syncthreads();                    // all waves done reading As
    #pragma unroll
    for (int i = 0; i < 4; i++) {
      int cb = wm*64 + i*16 + (lane >> 4)*4;
      #pragma unroll
      for (int j = 0; j < 2; j++) {
        int ll = wn*32 + j*16 + (lane & 15);
        #pragma unroll
        for (int r = 0; r < 4; r++)
          T[(cb + r)*66 + ll] = f2bf(acc[i][j][r]);
      }
    }
    __syncthreads();
    const int b2 = M0 >> 11, c0 = M0 & (INNER_-1);
    u16* yc = (u16*)Cout;
    #pragma unroll
    for (int q = 0; q < (TM*TN/8)/NTHR; q++) {
      int task = q*NTHR + t;
      int cg = task & 15, ll = task >> 4;
      union { u16 a[8]; short8 v8; } tu;
      #pragma unroll
      for (int e = 0; e < 8; e++) tu.a[e] = T[(cg*8 + e)*66 + ll];
      *(short8*)&yc[((size_t)((b2 << 10) + N0 + ll) << 12) + 2048 + c0 + cg*8] = tu.v8;
    }
  } else {
    // C/D layout: col = lane&15, row = (lane>>4)*4 + r
    #pragma unroll
    for (int i = 0; i < 4; i++) {
      int mbase = M0 + wm*64 + i*16 + (lane >> 4)*4;
      #pragma unroll
      for (int j = 0; j < 2; j++) {
        int n = N0 + wn*32 + j*16 + (lane & 15);
        #pragma unroll
        for (int r = 0; r < 4; r++) {
          int m = mbase + r;
          float v = acc[i][j][r];
          if (EPI == 0) {
            ((float*)Cout)[(size_t)m*ldc + n] = v;
          } else if (EPI == 3) {        // spectral filter, complex pair via shfl
            float pv = __shfl_xor(v, 1, 64);
            int f = n >> 1;
            float outv = 0.f;
            if (f < NFFT_) {
              int c = m & (INNER_-1);
              float d  = fexp_(-aux2[c] * (float)f * (1.f/512.f));
              float wr = aux0[c*NFFT_+f]*d, wi = aux3[c*NFFT_+f]*d;
              float a = (n & 1) ? pv : v;
              float b = (n & 1) ? v : pv;
              outv = (n & 1) ? (a*wi + b*wr) : (a*wr - b*wi);
            }
            ((u16*)Cout)[(size_t)m*ldc + n] = f2bf(outv);
          } else if (EPI == 7) {        // f32 split-K partial
            float* P = (float*)Cout + (size_t)ks * ((size_t)gy*TM*ldc);
            P[(size_t)m*ldc + n] = v;
          } else {                      // 8: bf16 split-K partial
            u16* P = (u16*)Cout + (size_t)ks * ((size_t)gy*TM*ldc);
            P[(size_t)m*ldc + n] = f2bf(v);
          }
        }
      }
    }
  }
}

// ---------------- fusion combine: gate epilogue over bf16 partials ----------
__global__ __launch_bounds__(256) void combine_gate_k(
    const u16* __restrict__ P, const float* __restrict__ fus_b,
    const u16* __restrict__ ycat, const float* __restrict__ xz,
    u16* __restrict__ ycomb)
{
  int i4 = (blockIdx.x*256 + threadIdx.x)*4;   // m*2048 + n
  int m = i4 >> 11, n = i4 & 2047;
  ushort4 p0 = *(const ushort4*)(P + i4);
  ushort4 p1 = *(const ushort4*)(P + 4194304 + i4);
  ushort4 ysv = *(const ushort4*)(ycat + (size_t)m*4096 + n);
  ushort4 ypv = *(const ushort4*)(ycat + (size_t)m*4096 + 2048 + n);
  float4 zv = *(const float4*)(xz + (size_t)m*4096 + 2048 + n);
  float4 fb = *(const float4*)(fus_b + n);
  float pp[4] = {bf2f(p0.x)+bf2f(p1.x), bf2f(p0.y)+bf2f(p1.y),
                 bf2f(p0.z)+bf2f(p1.z), bf2f(p0.w)+bf2f(p1.w)};
  float zz[4] = {zv.x, zv.y, zv.z, zv.w};
  float bb[4] = {fb.x, fb.y, fb.z, fb.w};
  u16 ys[4] = {ysv.x, ysv.y, ysv.z, ysv.w};
  u16 yp[4] = {ypv.x, ypv.y, ypv.z, ypv.w};
  ushort4 o;
  u16* op = (u16*)&o;
  #pragma unroll
  for (int j = 0; j < 4; j++) {
    float g = fsigm_(pp[j] + bb[j]);
    op[j] = f2bf((g*bf2f(ys[j]) + (1.f-g)*bf2f(yp[j]))*fsilu_(zz[j]));
  }
  *(ushort4*)(ycomb + i4) = o;
}

// ---------------- SSM chunked scan (prefetched) ----------------
__global__ __launch_bounds__(256) void scan1_k(
    const float* __restrict__ xdbc, const float* __restrict__ xconv,
    const float* __restrict__ A_log, const float* __restrict__ dtw,
    const float* __restrict__ dtb, float* __restrict__ Pq)
{
  int idx = blockIdx.x*256 + threadIdx.x;   // (b*NCH+ch)*INNER + e
  int e  = idx & (INNER_-1);
  int bc = idx >> 11;
  int ch = bc & (NCH_-1);
  int b  = bc >> 5;
  float A[STATE_];
  #pragma unroll
  for (int s=0;s<STATE_;s++) A[s] = -fexp_(A_log[e*STATE_+s]);
  float w[DTR_];
  #pragma unroll
  for (int r=0;r<DTR_;r++) w[r] = dtw[e*DTR_+r];
  float bias = dtb[e];
  float h[STATE_] = {};
  float sdt = 0.f;
  int mbase = b*L_ + ch*CHL_;
  float dtx[DTR_], Bv[STATE_], xcv;
  {
    const float* row = xdbc + (size_t)mbase*40;
    #pragma unroll
    for (int r=0;r<DTR_;r++) dtx[r] = row[r];
    #pragma unroll
    for (int s=0;s<STATE_;s++) Bv[s] = row[8+s];
    xcv = xconv[(size_t)mbase*INNER_ + e];
  }
  for (int l=0;l<CHL_;l++) {
    float ndtx[DTR_], nBv[STATE_], nxcv = 0.f;
    if (l+1 < CHL_) {
      const float* nrow = xdbc + (size_t)(mbase+l+1)*40;
      #pragma unroll
      for (int r=0;r<DTR_;r++) ndtx[r] = nrow[r];
      #pragma unroll
      for (int s=0;s<STATE_;s++) nBv[s] = nrow[8+s];
      nxcv = xconv[(size_t)(mbase+l+1)*INNER_ + e];
    } else {
      #pragma unroll
      for (int r=0;r<DTR_;r++) ndtx[r] = 0.f;
      #pragma unroll
      for (int s=0;s<STATE_;s++) nBv[s] = 0.f;
    }
    float v = bias;
    #pragma unroll
    for (int r=0;r<DTR_;r++) v += dtx[r]*w[r];
    float dt = fsoftplus_(v);
    sdt += dt;
    float dx = dt * xcv;
    #pragma unroll
    for (int s=0;s<STATE_;s++) {
      float dA = fexp_(dt*A[s]);
      h[s] = dA*h[s] + dx*Bv[s];
    }
    #pragma unroll
    for (int r=0;r<DTR_;r++) dtx[r] = ndtx[r];
    #pragma unroll
    for (int s=0;s<STATE_;s++) Bv[s] = nBv[s];
    xcv = nxcv;
  }
  float* o = Pq + (size_t)idx*32;
  #pragma unroll
  for (int s=0;s<STATE_;s++) { o[s] = fexp_(A[s]*sdt); o[16+s] = h[s]; }
}

__global__ __launch_bounds__(256) void scan2_k(float* __restrict__ Pq)
{
  int idx = blockIdx.x*256 + threadIdx.x;   // 65536
  int s = idx & 15;
  int e = (idx >> 4) & (INNER_-1);
  int b = idx >> 15;
  float h = 0.f;
  for (int ch = 0; ch < NCH_; ch++) {
    size_t base = ((size_t)(b*NCH_+ch)*INNER_ + e)*32;
    float p = Pq[base + s];
    float q = Pq[base + 16 + s];
    Pq[base + 16 + s] = h;
    h = p*h + q;
  }
}

__global__ __launch_bounds__(256) void scan3_k(
    const float* __restrict__ xdbc, const float* __restrict__ xconv,
    const float* __restrict__ A_log, const float* __restrict__ dtw,
    const float* __restrict__ dtb, const float* __restrict__ Dp,
    const float* __restrict__ Pq, u16* __restrict__ ycat)
{
  int idx = blockIdx.x*256 + threadIdx.x;
  int e  = idx & (INNER_-1);
  int bc = idx >> 11;
  int ch = bc & (NCH_-1);
  int b  = bc >> 5;
  float A[STATE_];
  #pragma unroll
  for (int s=0;s<STATE_;s++) A[s] = -fexp_(A_log[e*STATE_+s]);
  float w[DTR_];
  #pragma unroll
  for (int r=0;r<DTR_;r++) w[r] = dtw[e*DTR_+r];
  float bias = dtb[e];
  float Dv = Dp[e];
  float h[STATE_];
  const float* hi = Pq + (size_t)idx*32 + 16;
  #pragma unroll
  for (int s=0;s<STATE_;s++) h[s] = hi[s];
  int mbase = b*L_ + ch*CHL_;
  float dtx[DTR_], Bv[STATE_], Cv[STATE_], xcv;
  {
    const float* row = xdbc + (size_t)mbase*40;
    #pragma unroll
    for (int r=0;r<DTR_;r++) dtx[r] = row[r];
    #pragma unroll
    for (int s=0;s<STATE_;s++) { Bv[s] = row[8+s]; Cv[s] = row[24+s]; }
    xcv = xconv[(size_t)mbase*INNER_ + e];
  }
  for (int l=0;l<CHL_;l++) {
    float ndtx[DTR_], nBv[STATE_], nCv[STATE_], nxcv = 0.f;
    if (l+1 < CHL_) {
      const float* nrow = xdbc + (size_t)(mbase+l+1)*40;
      #pragma unroll
      for (int r=0;r<DTR_;r++) ndtx[r] = nrow[r];
      #pragma unroll
      for (int s=0;s<STATE_;s++) { nBv[s] = nrow[8+s]; nCv[s] = nrow[24+s]; }
      nxcv = xconv[(size_t)(mbase+l+1)*INNER_ + e];
    } else {
      #pragma unroll
      for (int r=0;r<DTR_;r++) ndtx[r] = 0.f;
      #pragma unroll
      for (int s=0;s<STATE_;s++) { nBv[s] = 0.f; nCv[s] = 0.f; }
    }
    float v = bias;
    #pragma unroll
    for (int r=0;r<DTR_;r++) v += dtx[r]*w[r];
    float dt = fsoftplus_(v);
    float dx = dt * xcv;
    float y = 0.f;
    #pragma unroll
    for (int s=0;s<STATE_;s++) {
      float dA = fexp_(dt*A[s]);
      h[s] = dA*h[s] + dx*Bv[s];
      y += h[s]*Cv[s];
    }
    ycat[(size_t)(mbase+l)*4096 + e] = f2bf(y + xcv*Dv);
    #pragma unroll
    for (int r=0;r<DTR_;r++) dtx[r] = ndtx[r];
    #pragma unroll
    for (int s=0;s<STATE_;s++) { Bv[s] = nBv[s]; Cv[s] = nCv[s]; }
    xcv = nxcv;
  }
}

// ---------------- layernorm over summed out_proj partials + residual --------
__global__ __launch_bounds__(256) void ln2_k(const float* __restrict__ Q,
    const float* __restrict__ xres,
    const float* __restrict__ gma, const float* __restrict__ bta,
    float* __restrict__ out)
{
  int m = blockIdx.x;
  float s=0.f, s2=0.f;
  float v[4];
  #pragma unroll
  for (int j=0;j<4;j++) {
    int n = threadIdx.x + j*256;
    size_t idx = (size_t)m*DM_ + n;
    v[j] = Q[idx] + Q[2097152 + idx] + xres[idx];
    s += v[j]; s2 += v[j]*v[j];
  }
  #pragma unroll
  for (int off=32; off>=1; off>>=1) {
    s  += __shfl_down(s, off);
    s2 += __shfl_down(s2, off);
  }
  __shared__ float rs[4], rs2[4], stats[2];
  int wid = threadIdx.x >> 6;
  if ((threadIdx.x & 63) == 0) { rs[wid]=s; rs2[wid]=s2; }
  __syncthreads();
  if (threadIdx.x == 0) {
    float ts  = rs[0]+rs[1]+rs[2]+rs[3];
    float ts2 = rs2[0]+rs2[1]+rs2[2]+rs2[3];
    float mu  = ts/(float)DM_;
    float var = ts2/(float)DM_ - mu*mu;
    stats[0] = mu; stats[1] = rsqrtf(var + 1e-5f);
  }
  __syncthreads();
  float mu = stats[0], rstd = stats[1];
  #pragma unroll
  for (int j=0;j<4;j++) {
    int n = threadIdx.x + j*256;
    out[(size_t)m*DM_ + n] = (v[j]-mu)*rstd*gma[n] + bta[n];
  }
}

extern "C" void kernel_launch(void* const* d_in, const int* in_sizes, int n_in,
                              void* d_out, int out_size, void* d_ws, size_t ws_size,
                              hipStream_t stream)
{
  const float* x       = (const float*)d_in[0];
  const float* in_w    = (const float*)d_in[1];
  const float* conv_w  = (const float*)d_in[2];
  const float* conv_b  = (const float*)d_in[3];
  const float* A_log   = (const float*)d_in[4];
  const float* Dp      = (const float*)d_in[5];
  const float* xproj_w = (const float*)d_in[6];
  const float* dt_w    = (const float*)d_in[7];
  const float* dt_b    = (const float*)d_in[8];
  const float* f_re    = (const float*)d_in[9];
  const float* f_im    = (const float*)d_in[10];
  const float* s_dec   = (const float*)d_in[11];
  const float* fus_w   = (const float*)d_in[12];
  const float* fus_b   = (const float*)d_in[13];
  const float* out_w   = (const float*)d_in[14];
  const float* ln_g    = (const float*)d_in[15];
  const float* ln_b    = (const float*)d_in[16];
  float* out = (float*)d_out;

  // ---- workspace carve (fp32 region then bf16 region), ~137 MB total ----
  float* ws    = (float*)d_ws;
  float* xz    = ws;                       // 8388608  (M x 4096)
  float* xconv = xz    + 8388608;          // 4194304  (M x 2048)
  float* xdbc  = xconv + 4194304;          // 81920    (M x 40)
  float* Pq    = xdbc  + 81920;            // 4194304  (B*NCH*INNER x 32)
  u16* ub      = (u16*)(Pq + 4194304);
  u16* xb      = ub;                       // 2097152   x bf16; reused as Winv
  u16* inwb    = xb    + 2097152;          // 4194304   in_w bf16; reused as part
  u16* fuswb   = inwb  + 4194304;          // 8388608   fus_w bf16 (L1 aux)
  u16* outwb   = fuswb + 8388608;          // 2097152   out_w bf16 (L2 aux)
  u16* xt      = outwb + 2097152;          // 4194304   x_inner^T bf16; reused as ycomb
  u16* Wb      = xt    + 4194304;          // 1114112   Wdft (NFP_ x 1024)
  u16* XFb     = Wb    + 1114112;          // 4456448   (MD x NFP_) bf16
  u16* ycat    = XFb   + 4456448;          // 8388608   (M x 4096) bf16
  u16* ycomb   = xt;
  u16* Winv    = xb;                       // xb dead after L1
  float* part  = (float*)inwb;             // 1310720 f; inwb dead after L1
  u16* fpart   = (u16*)xconv;              // 8388608 u16 = xconv span (dead after scan3)
  float* opart = Pq;                       // 4194304 f (dead after scan3)

  // 0. convert x + in_w to bf16
  cvt2_k<<<CVT2_NT/1024, 256, 0, stream>>>(x, in_w, xb);

  // 1. xz = x @ in_proj_w^T (2048 x 4096 x 1024), plain f32 epilogue
  //    + aux genWdft (2176) + aux cvt fus_w (1024)
  mgemm_k<128,128,0,0,1,1><<<512 + 2176 + 1024, 512, 0, stream>>>(
      xb, inwb, xz, 1024, 4096, nullptr, nullptr, nullptr, nullptr, 32, 16,
      nullptr, nullptr, nullptr, Wb, 1024, fus_w, fuswb);
  // 2. conv+silu (writes xconv) + x_inner^T emit (writes xt, coalesced)
  //    + genWinv + cvt out_w   [standalone: 2048+4352+512 blocks]
  aux2_k<<<6912, 256, 0, stream>>>(xz, conv_w, conv_b, xconv, xt, Winv, out_w, outwb);
  // 3. forward DFT + spectral filter: XFb = filt(xt @ Wdft)  [544 GEMM blocks]
  //    + aux xproj (128)
  mgemm_k<128,64,3,1,3,1><<<544 + SK_*8, 256, 0, stream>>>(
      xt, Wb, XFb, 1024, NFP_, f_re, nullptr, s_dec, f_im, 17, 32,
      xconv, xproj_w, part, nullptr, 1024, nullptr, nullptr);
  // 4. inverse DFT (4096 x 1024 x NFP_), LDS-transpose epilogue -> ycat[:,2048:]
  //    [512 GEMM blocks] + aux xpred (320)
  mgemm_k<128,64,6,1,4,1><<<512 + 320, 256, 0, stream>>>(
      XFb, Winv, ycat, NFP_, 0, nullptr, nullptr, nullptr, nullptr, 16, 32,
      part, nullptr, xdbc, nullptr, NFP_, nullptr, nullptr);
  // 5-7. chunked SSM scan -> y_cat[:, :2048] (bf16)
  scan1_k<<<(B_*NCH_*INNER_)/256, 256, 0, stream>>>(xdbc, xconv, A_log, dt_w, dt_b, Pq);
  scan2_k<<<(B_*INNER_*STATE_)/256, 256, 0, stream>>>(Pq);
  scan3_k<<<(B_*NCH_*INNER_)/256, 256, 0, stream>>>(xdbc, xconv, A_log, dt_w, dt_b, Dp, Pq, ycat);
  // 8a. fusion GEMM split-K x2 (2048 x 2048 x 4096), bf16 partials -> fpart
  mgemm_k<128,128,8,0,0,2><<<2*256, 512, 0, stream>>>(
      ycat, fuswb, fpart, 2048, 2048, nullptr, nullptr, nullptr, nullptr, 16, 16,
      nullptr, nullptr, nullptr, nullptr, 4096, nullptr, nullptr);
  // 8b. combine partials + gate epilogue -> ycomb bf16
  combine_gate_k<<<(2048*2048/4)/256, 256, 0, stream>>>(
      fpart, fus_b, ycat, xz, ycomb);
  // 9. out proj split-K x2 (2048 x 1024 x 2048) -> f32 partials in opart
  mgemm_k<64,64,7,1,0,2><<<2*512, 128, 0, stream>>>(
      ycomb, outwb, opart, 1024, 1024, nullptr, nullptr, nullptr, nullptr, 16, 32,
      nullptr, nullptr, nullptr, nullptr, 2048, nullptr, nullptr);
  // 10. layernorm over (partial0 + partial1 + residual) -> d_out
  ln2_k<<<M_, 256, 0, stream>>>(opart, x, ln_g, ln_b, out);
}